// Round 5
// baseline (244.534 us; speedup 1.0000x reference)
//
#include <hip/hip_runtime.h>
#include <stdint.h>

// Problem constants
#define B_    2
#define NQ_   1024
#define NKV_  4096
#define DQ_   1024
#define H_    16
#define DH_   64
#define INNER_ 1024

typedef unsigned short u16;
typedef uint32_t u32;
typedef __bf16 bf16x8 __attribute__((ext_vector_type(8)));
typedef float  f32x4  __attribute__((ext_vector_type(4)));

__device__ __forceinline__ u16 f2bf(float x) {           // RNE
  union { float f; uint32_t u; } v; v.f = x;
  uint32_t r = v.u + 0x7FFFu + ((v.u >> 16) & 1u);
  return (u16)(r >> 16);
}
__device__ __forceinline__ u32 pack2(float a, float b) { // RNE pair
  return (u32)f2bf(a) | ((u32)f2bf(b) << 16);
}
__device__ __forceinline__ u32 pack2rn(float a, float b) { // fast RN via v_perm (3 VALU)
  union { float f; u32 u; } x, y; x.f = a; y.f = b;
  return __builtin_amdgcn_perm(y.u + 0x8000u, x.u + 0x8000u, 0x07060302u);
}
__device__ __forceinline__ float bf2f(u16 s) {
  union { float f; uint32_t u; } v; v.u = ((uint32_t)s) << 16; return v.f;
}

// async global->LDS, 16B/lane; lds base wave-uniform, hw adds lane*16
__device__ __forceinline__ void gload16(const void* g, void* l) {
  __builtin_amdgcn_global_load_lds((const __attribute__((address_space(1))) void*)g,
                                   (__attribute__((address_space(3))) void*)l,
                                   16, 0, 0);
}

// ---------------- fused prep: casts + weight transposes in ONE dispatch -----------------
// blocks [0,1280): fat casts (8 x float4 per thread); [1280,2304): Wq^T;
// [2304,4352): Wkv^T; [4352,5376): Wout^T.
__global__ __launch_bounds__(256) void prep(const float* __restrict__ x,
                                            const float* __restrict__ ctx,
                                            const float* __restrict__ Wq,
                                            const float* __restrict__ Wkv,
                                            const float* __restrict__ Wout,
                                            u16* __restrict__ xb,
                                            u16* __restrict__ ctxb,
                                            u16* __restrict__ WqT,
                                            u16* __restrict__ WkvT,
                                            u16* __restrict__ WoutT) {
  int bid = blockIdx.x;
  if (bid < 1280) {                        // elementwise cast, 32 elems/thread
    const float* src; u16* dst; int fbase;  // float4 units
    if (bid < 256) { src = x;   dst = xb;   fbase = bid * 2048; }
    else           { src = ctx; dst = ctxb; fbase = (bid - 256) * 2048; }
#pragma unroll
    for (int u = 0; u < 8; ++u) {
      int i = (fbase + u * 256 + threadIdx.x) * 4;
      float4 v = *(const float4*)(src + i);
      uint2 o; o.x = pack2(v.x, v.y); o.y = pack2(v.z, v.w);
      *(uint2*)(dst + i) = o;
    }
    return;
  }
  // transpose+cast W[K][N] -> Wt[N][K]
  __shared__ float tile[32][33];
  const float* W; u16* Wt; int K, N, local, nsh;
  int b2 = bid - 1280;
  if (b2 < 1024)      { W = Wq;   Wt = WqT;   K = 1024; N = 1024; local = b2;        nsh = 5; }
  else if (b2 < 3072) { W = Wkv;  Wt = WkvT;  K = 1024; N = 2048; local = b2 - 1024; nsh = 6; }
  else                { W = Wout; Wt = WoutT; K = 1024; N = 1024; local = b2 - 3072; nsh = 5; }
  int n0 = (local & ((1 << nsh) - 1)) * 32;
  int k0 = (local >> nsh) * 32;
  int tx = threadIdx.x & 31, ty = threadIdx.x >> 5;   // 32 x 8
  for (int i = ty; i < 32; i += 8)
    tile[i][tx] = W[(size_t)(k0 + i) * N + n0 + tx];
  __syncthreads();
  for (int i = ty; i < 32; i += 8)
    Wt[(size_t)(n0 + i) * K + k0 + tx] = f2bf(tile[tx][i]);
}

// ---------------- kv projection: 256x256 / BK=64 / 8-wave 8-phase pipelined GEMM --------
// Round-1 proven (main loop + epilogues). K row-major; V transposed scatter.
__global__ __launch_bounds__(512, 2) void kv_gemm(const u16* __restrict__ ctxb,
                                                  const u16* __restrict__ WkvT,
                                                  u16* __restrict__ kb,
                                                  u16* __restrict__ vTb) {
  __shared__ __align__(16) u16 As[2][256 * 64];   // 64 KiB
  __shared__ __align__(16) u16 Bs[2][256 * 64];   // 64 KiB
  const int tid = threadIdx.x;
  const int lane = tid & 63;
  const int w = tid >> 6;                 // 0..7
  const int wr = w >> 2, wc = w & 3;      // 2 x 4 waves -> wave panel 128M x 64N
  const int l15 = lane & 15, quad = lane >> 4;
  const int K = 1024;

  // XCD-chunked bijective swizzle: each XCD gets 4 contiguous M-strips x all 8 N-tiles
  int bid = blockIdx.x;
  int wgid = (bid & 7) * 32 + (bid >> 3);
  const int tm = wgid >> 3, tn = wgid & 7;
  const int m0 = tm * 256, n0 = tn * 256;
  const u16* Ag = ctxb + (size_t)m0 * K;
  const u16* Bg = WkvT + (size_t)n0 * K;

  // per-thread stage source offsets (u16 units): row-reorder + chunk XOR pre-swizzle
  size_t offA[2][2], offB[2][2];          // [half][pass] - all uses const-indexed
#pragma unroll
  for (int ah = 0; ah < 2; ++ah)
#pragma unroll
    for (int p = 0; p < 2; ++p) {
      int c = p * 512 + (w << 6) + lane;  // chunk id within 16 KiB region
      int s = ah * 128 + (c >> 3);        // LDS slot (reordered row)
      int col = ((c & 7) ^ (s & 7)) << 3; // pre-swizzled source column (bf16)
      int rA = ((s >> 6) & 1) * 128 + ((s >> 7) & 1) * 64 + (s & 63);
      int rB = ((s >> 5) & 3) * 64 + ((s >> 7) & 1) * 32 + (s & 31);
      offA[ah][p] = (size_t)rA * 1024 + col;
      offB[ah][p] = (size_t)rB * 1024 + col;
    }

#define STAGE_A(bufi, ah, kk) do { \
    gload16(Ag + offA[ah][0] + (kk), &As[bufi][(ah) * 8192 + (w << 9)]); \
    gload16(Ag + offA[ah][1] + (kk), &As[bufi][(ah) * 8192 + 4096 + (w << 9)]); \
  } while (0)
#define STAGE_B(bufi, bh, kk) do { \
    gload16(Bg + offB[bh][0] + (kk), &Bs[bufi][(bh) * 8192 + (w << 9)]); \
    gload16(Bg + offB[bh][1] + (kk), &Bs[bufi][(bh) * 8192 + 4096 + (w << 9)]); \
  } while (0)
#define LDA2(dst, i8, bufi) do { \
    const int _s = ((i8) >> 2) * 128 + wr * 64 + ((i8) & 3) * 16 + l15; \
    const u16* _p = &As[bufi][_s * 64]; const int _x = _s & 7; \
    dst[0] = *(const bf16x8*)&_p[(quad ^ _x) << 3]; \
    dst[1] = *(const bf16x8*)&_p[((quad + 4) ^ _x) << 3]; \
  } while (0)
#define LDB2(dst, j, bufi) do { \
    const int _s = ((j) >> 1) * 128 + wc * 32 + ((j) & 1) * 16 + l15; \
    const u16* _p = &Bs[bufi][_s * 64]; const int _x = _s & 7; \
    dst[0] = *(const bf16x8*)&_p[(quad ^ _x) << 3]; \
    dst[1] = *(const bf16x8*)&_p[((quad + 4) ^ _x) << 3]; \
  } while (0)
#define MF(i0, j0, bb) do { \
    _Pragma("unroll") \
    for (int _i = 0; _i < 4; ++_i) { \
      acc[(i0) + _i][(j0)    ] = __builtin_amdgcn_mfma_f32_16x16x32_bf16(a[_i][0], bb[0][0], acc[(i0) + _i][(j0)    ], 0, 0, 0); \
      acc[(i0) + _i][(j0)    ] = __builtin_amdgcn_mfma_f32_16x16x32_bf16(a[_i][1], bb[0][1], acc[(i0) + _i][(j0)    ], 0, 0, 0); \
      acc[(i0) + _i][(j0) + 1] = __builtin_amdgcn_mfma_f32_16x16x32_bf16(a[_i][0], bb[1][0], acc[(i0) + _i][(j0) + 1], 0, 0, 0); \
      acc[(i0) + _i][(j0) + 1] = __builtin_amdgcn_mfma_f32_16x16x32_bf16(a[_i][1], bb[1][1], acc[(i0) + _i][(j0) + 1], 0, 0, 0); \
    } \
  } while (0)

  f32x4 acc[8][4] = {};
  bf16x8 a[4][2], b[2][2], c2[2][2];

  // prologue: full tile 0 into buf 0; queue = [Aa, Ba, Bb, Ab]
  STAGE_A(0, 0, 0);
  STAGE_B(0, 0, 0);
  STAGE_B(0, 1, 0);
  STAGE_A(0, 1, 0);
  asm volatile("s_waitcnt vmcnt(4)" ::: "memory");   // Aa,Ba ready
  __builtin_amdgcn_s_barrier();

#define KTILE(cur, nxt, kk, STG, W1, W2) do { \
    /* ph1: quadrant (ih0, jh0); reads Aa+Ba regions */ \
    LDB2(b[0], 0, cur); LDB2(b[1], 1, cur); \
    LDA2(a[0], 0, cur); LDA2(a[1], 1, cur); LDA2(a[2], 2, cur); LDA2(a[3], 3, cur); \
    if (STG) STAGE_A(nxt, 0, kk); \
    __builtin_amdgcn_s_barrier(); \
    asm volatile("s_waitcnt lgkmcnt(0)" ::: "memory"); \
    __builtin_amdgcn_s_setprio(1); MF(0, 0, b); __builtin_amdgcn_s_setprio(0); \
    asm volatile("s_waitcnt " W1 ::: "memory"); \
    __builtin_amdgcn_s_barrier(); \
    /* ph2: (ih0, jh1); reads Bb region */ \
    LDB2(c2[0], 2, cur); LDB2(c2[1], 3, cur); \
    if (STG) STAGE_B(nxt, 0, kk); \
    __builtin_amdgcn_s_barrier(); \
    asm volatile("s_waitcnt lgkmcnt(0)" ::: "memory"); \
    __builtin_amdgcn_s_setprio(1); MF(0, 2, c2); __builtin_amdgcn_s_setprio(0); \
    asm volatile("s_waitcnt " W2 ::: "memory"); \
    __builtin_amdgcn_s_barrier(); \
    /* ph3: (ih1, jh0); reads Ab region */ \
    LDA2(a[0], 4, cur); LDA2(a[1], 5, cur); LDA2(a[2], 6, cur); LDA2(a[3], 7, cur); \
    if (STG) STAGE_B(nxt, 1, kk); \
    __builtin_amdgcn_s_barrier(); \
    asm volatile("s_waitcnt lgkmcnt(0)" ::: "memory"); \
    __builtin_amdgcn_s_setprio(1); MF(4, 0, b); __builtin_amdgcn_s_setprio(0); \
    __builtin_amdgcn_s_barrier(); \
    /* ph4: (ih1, jh1); no ds_read */ \
    if (STG) STAGE_A(nxt, 1, kk); \
    __builtin_amdgcn_s_barrier(); \
    __builtin_amdgcn_s_setprio(1); MF(4, 2, c2); __builtin_amdgcn_s_setprio(0); \
    if (STG) { asm volatile("s_waitcnt vmcnt(4)" ::: "memory"); } \
    __builtin_amdgcn_s_barrier(); \
  } while (0)

  for (int T = 0; T < 15; ++T) {
    const int cur = T & 1, nxt = cur ^ 1, kk = (T + 1) * 64;
    KTILE(cur, nxt, kk, 1, "vmcnt(4)", "vmcnt(4)");
  }
  KTILE(1, 0, 0, 0, "vmcnt(2)", "vmcnt(0)");   // tail: nothing staged

  // epilogue (round-1 proven): tn<4 -> K row-major, tn>=4 -> V transposed scatter
  if (tn < 4) {
#pragma unroll
    for (int i8 = 0; i8 < 8; ++i8)
#pragma unroll
      for (int j = 0; j < 4; ++j) {
        int col = n0 + wc * 64 + j * 16 + l15;
#pragma unroll
        for (int r = 0; r < 4; ++r) {
          int row = m0 + wr * 128 + i8 * 16 + quad * 4 + r;
          kb[(size_t)row * 1024 + col] = f2bf(acc[i8][j][r]);
        }
      }
  } else {
    const int bb_ = m0 >> 12;
#pragma unroll
    for (int i8 = 0; i8 < 8; ++i8) {
      int kvr = (m0 & 4095) + wr * 128 + i8 * 16 + quad * 4;
#pragma unroll
      for (int j = 0; j < 4; ++j) {
        int c = (n0 - 1024) + wc * 64 + j * 16 + l15;
        int h = c >> 6, dh = c & 63;
        uint2 st;
        st.x = pack2(acc[i8][j][0], acc[i8][j][1]);
        st.y = pack2(acc[i8][j][2], acc[i8][j][3]);
        *(uint2*)&vTb[((size_t)((bb_ * 16 + h) * 64 + dh)) * NKV_ + kvr] = st;
      }
    }
  }
#undef STAGE_A
#undef STAGE_B
#undef LDA2
#undef LDB2
#undef MF
#undef KTILE
}

// ---------------- q projection: 64x128 tiles -> 256 blocks (full GPU), bf16 out ---------
__global__ __launch_bounds__(256) void q_gemm(const u16* __restrict__ A,
                                              const u16* __restrict__ Bt,
                                              u16* __restrict__ outp) {
  __shared__ __align__(16) u16 As[64 * 32];    // 4 KB
  __shared__ __align__(16) u16 Bs[128 * 32];   // 8 KB
  const int tid = threadIdx.x;
  const int lane = tid & 63;
  const int w = tid >> 6;
  const int wr = w >> 1, wc = w & 1;           // wave covers 32M x 64N
  const int l15 = lane & 15, quad = lane >> 4;
  const int unit = blockIdx.x;
  const int m0 = (unit >> 3) * 64, n0 = (unit & 7) * 128;
  const int K = 1024, N = 1024;

  const u16* Ab = A + (size_t)m0 * K;
  const u16* Bb = Bt + (size_t)n0 * K;
  f32x4 acc[2][4] = {};

  const int ar = tid >> 2, ac = (tid & 3) << 3;          // A: 256 chunks, 1/thread
  const int q1 = w * 64 + lane, q2 = q1 + 256;           // B: 512 chunks, 2/thread
  const int br1 = q1 >> 2, bc1 = (q1 & 3) << 3;
  const int br2 = q2 >> 2, bc2 = (q2 & 3) << 3;

  for (int k0 = 0; k0 < K; k0 += 32) {
    __syncthreads();
    gload16(Ab + (size_t)ar * K + k0 + ac, &As[w * 512]);
    gload16(Bb + (size_t)br1 * K + k0 + bc1, &Bs[w * 512]);
    gload16(Bb + (size_t)br2 * K + k0 + bc2, &Bs[2048 + w * 512]);
    __syncthreads();
    bf16x8 af[2], bfr[4];
#pragma unroll
    for (int i = 0; i < 2; ++i)
      af[i] = *(const bf16x8*)&As[(wr * 32 + i * 16 + l15) * 32 + quad * 8];
#pragma unroll
    for (int j = 0; j < 4; ++j)
      bfr[j] = *(const bf16x8*)&Bs[(wc * 64 + j * 16 + l15) * 32 + quad * 8];
#pragma unroll
    for (int i = 0; i < 2; ++i)
#pragma unroll
      for (int j = 0; j < 4; ++j)
        acc[i][j] = __builtin_amdgcn_mfma_f32_16x16x32_bf16(af[i], bfr[j], acc[i][j], 0, 0, 0);
  }

#pragma unroll
  for (int i = 0; i < 2; ++i)
#pragma unroll
    for (int j = 0; j < 4; ++j) {
      int col = n0 + wc * 64 + j * 16 + l15;
#pragma unroll
      for (int r = 0; r < 4; ++r) {
        int row = m0 + wr * 32 + i * 16 + quad * 4 + r;
        outp[(size_t)row * N + col] = f2bf(acc[i][j][r]);
      }
    }
}

// ---------------- out-proj GEMM: 64x128 tiles -> 256 blocks (full GPU) ------------------
__global__ __launch_bounds__(256) void out_gemm(const u16* __restrict__ A,
                                                const u16* __restrict__ Bt,
                                                float* __restrict__ Cout,
                                                const float* __restrict__ bias) {
  __shared__ __align__(16) u16 As[64 * 32];    // 4 KB
  __shared__ __align__(16) u16 Bs[128 * 32];   // 8 KB
  const int tid = threadIdx.x;
  const int lane = tid & 63;
  const int w = tid >> 6;
  const int wr = w >> 1, wc = w & 1;           // wave covers 32M x 64N
  const int l15 = lane & 15, quad = lane >> 4;
  const int unit = blockIdx.x;
  const int m0 = (unit >> 3) * 64, n0 = (unit & 7) * 128;
  const int K = 1024, N = 1024;

  const u16* Ab = A + (size_t)m0 * K;
  const u16* Bb = Bt + (size_t)n0 * K;
  f32x4 acc[2][4] = {};

  const int ar = tid >> 2, ac = (tid & 3) << 3;          // A: 256 chunks, 1/thread
  const int q1 = w * 64 + lane, q2 = q1 + 256;           // B: 512 chunks, 2/thread
  const int br1 = q1 >> 2, bc1 = (q1 & 3) << 3;
  const int br2 = q2 >> 2, bc2 = (q2 & 3) << 3;

  for (int k0 = 0; k0 < K; k0 += 32) {
    __syncthreads();
    gload16(Ab + (size_t)ar * K + k0 + ac, &As[w * 512]);
    gload16(Bb + (size_t)br1 * K + k0 + bc1, &Bs[w * 512]);
    gload16(Bb + (size_t)br2 * K + k0 + bc2, &Bs[2048 + w * 512]);
    __syncthreads();
    bf16x8 af[2], bfr[4];
#pragma unroll
    for (int i = 0; i < 2; ++i)
      af[i] = *(const bf16x8*)&As[(wr * 32 + i * 16 + l15) * 32 + quad * 8];
#pragma unroll
    for (int j = 0; j < 4; ++j)
      bfr[j] = *(const bf16x8*)&Bs[(wc * 64 + j * 16 + l15) * 32 + quad * 8];
#pragma unroll
    for (int i = 0; i < 2; ++i)
#pragma unroll
      for (int j = 0; j < 4; ++j)
        acc[i][j] = __builtin_amdgcn_mfma_f32_16x16x32_bf16(af[i], bfr[j], acc[i][j], 0, 0, 0);
  }

#pragma unroll
  for (int i = 0; i < 2; ++i)
#pragma unroll
    for (int j = 0; j < 4; ++j) {
      int col = n0 + wc * 64 + j * 16 + l15;
      float bv = bias[col];
#pragma unroll
      for (int r = 0; r < 4; ++r) {
        int row = m0 + wr * 32 + i * 16 + quad * 4 + r;
        Cout[(size_t)row * N + col] = acc[i][j][r] + bv;
      }
    }
}

// ---------------- flash attention: QBLK=32, 1024 blocks, 3 blocks/CU --------------------
// R4 structure (proven-correct staging/swizzle/fragment math) with the q-block halved:
// 32 q-rows per block -> grid dim3(32,32) = 1024 blocks -> 3 blocks/CU resident
// (LDS 43.5 KB, launch_bounds(256,3)) = 12 waves/CU. R2/R3/R4 established the stall is
// latency at 2 blocks/CU (stage-overlap was null); this attacks it with TLP. All
// fragment/LDS index math is wave-private and QBLK-independent; only t-loop bounds
// (4->2), q prologue, and the epilogue (waves 0/1 own q-tiles 0/1) change.
__global__ __launch_bounds__(256, 3) void attn_kernel(const u16* __restrict__ qg,
                                                      const u16* __restrict__ kb,
                                                      const u16* __restrict__ vT,
                                                      u16* __restrict__ attn_out) {
  __shared__ __align__(16) u16 Ks[128 * 64];       // [kv][dh], 16B groups XOR-swizzled
  __shared__ __align__(16) u16 Vs[64 * 128];       // [dh][kv], XOR-swizzled (16 groups/row)
  __shared__ __align__(16) u32 P32[4 * 2 * 16 * 20]; // [w][t][q=l15][20]: wave-private pairs
  __shared__ float Lr[4][2][16];                   // [w][t][q] partial l

  const int tid = threadIdx.x;
  const int lane = tid & 63;
  const int w = tid >> 6;
  const int l15 = lane & 15, quad = lane >> 4;
  const int bh = blockIdx.x, b = bh >> 4, h = bh & 15;
  const int q0 = blockIdx.y * 32;

  const float SC = 0.125f * 1.44269504088896340736f;   // dh^-0.5 * log2(e)
  union { u16 s[8]; bf16x8 v; } qf[2][2];
#pragma unroll
  for (int t = 0; t < 2; ++t)
#pragma unroll
    for (int kc = 0; kc < 2; ++kc) {
      const u16* qp = qg + (size_t)(b * NQ_ + q0 + t * 16 + l15) * INNER_ + h * 64 +
                      kc * 32 + quad * 8;
      union { u16 s[8]; uint4 u; } tmp;
      tmp.u = *(const uint4*)qp;
#pragma unroll
      for (int e = 0; e < 8; ++e) qf[t][kc].s[e] = f2bf(bf2f(tmp.s[e]) * SC);
    }

#define STAGEKV(j0) do { \
    _Pragma("unroll") \
    for (int i_ = 0; i_ < 4; ++i_) { \
      int s_ = i_ * 256 + tid; \
      int kr = s_ >> 3, kg = (s_ ^ kr) & 7; \
      gload16(kb + (size_t)(b * NKV_ + (j0) + kr) * 1024 + h * 64 + kg * 8, \
              &Ks[(i_ * 256 + w * 64) * 8]); \
      int vr = s_ >> 4, vg = (s_ ^ vr) & 15; \
      gload16(vT + (size_t)(bh * 64 + vr) * NKV_ + (j0) + vg * 8, \
              &Vs[(i_ * 256 + w * 64) * 8]); \
    } \
  } while (0)

  f32x4 Oacc[4][2] = {};
  float l_lane[2] = {0.f, 0.f};

  STAGEKV(0);                                // prologue: tile 0

  for (int it = 0; it < 32; ++it) {
    __syncthreads();                         // tile `it` staged (vmcnt drained per-wave)

    // fragment reads for tile `it` (this wave's complete K/V consumption)
    bf16x8 kf[2][2];
#pragma unroll
    for (int kvt = 0; kvt < 2; ++kvt)
#pragma unroll
      for (int kc = 0; kc < 2; ++kc)
        kf[kvt][kc] = *(const bf16x8*)
          &Ks[(w * 32 + kvt * 16 + l15) * 64 + (((kc * 4 + quad) ^ l15) & 7) * 8];
    bf16x8 vf[4];
#pragma unroll
    for (int d = 0; d < 4; ++d)
      vf[d] = *(const bf16x8*)
        &Vs[(d * 16 + l15) * 128 + (((w * 4 + quad) ^ l15) & 15) * 8];

    __syncthreads();                         // all waves done reading Ks/Vs

    if (it < 31) STAGEKV((it + 1) * 128);    // overwrite: overlaps full compute below

    f32x4 sacc[2][2] = {};
    __builtin_amdgcn_s_setprio(1);
#pragma unroll
    for (int kvt = 0; kvt < 2; ++kvt)
#pragma unroll
      for (int t = 0; t < 2; ++t)
#pragma unroll
        for (int kc = 0; kc < 2; ++kc)
          sacc[kvt][t] = __builtin_amdgcn_mfma_f32_16x16x32_bf16(
              kf[kvt][kc], qf[t][kc].v, sacc[kvt][t], 0, 0, 0);
    __builtin_amdgcn_s_setprio(0);

#pragma unroll
    for (int kvt = 0; kvt < 2; ++kvt)
#pragma unroll
      for (int t = 0; t < 2; ++t) {
        float p0 = __builtin_amdgcn_exp2f(sacc[kvt][t][0]);
        float p1 = __builtin_amdgcn_exp2f(sacc[kvt][t][1]);
        float p2 = __builtin_amdgcn_exp2f(sacc[kvt][t][2]);
        float p3 = __builtin_amdgcn_exp2f(sacc[kvt][t][3]);
        l_lane[t] += (p0 + p1) + (p2 + p3);
        uint2 pk; pk.x = pack2rn(p0, p1); pk.y = pack2rn(p2, p3);
        *(uint2*)&P32[((w * 2 + t) * 16 + l15) * 20 + kvt * 8 + quad * 2] = pk;
      }

    bf16x8 pf[2];
#pragma unroll
    for (int t = 0; t < 2; ++t)
      pf[t] = *(const bf16x8*)&P32[((w * 2 + t) * 16 + l15) * 20 + quad * 4];
    __builtin_amdgcn_s_setprio(1);
#pragma unroll
    for (int d = 0; d < 4; ++d)
#pragma unroll
      for (int t = 0; t < 2; ++t)
        Oacc[d][t] = __builtin_amdgcn_mfma_f32_16x16x32_bf16(vf[d], pf[t], Oacc[d][t],
                                                             0, 0, 0);
    __builtin_amdgcn_s_setprio(0);
  }
#undef STAGEKV

#pragma unroll
  for (int t = 0; t < 2; ++t) {
    l_lane[t] += __shfl_xor(l_lane[t], 16);
    l_lane[t] += __shfl_xor(l_lane[t], 32);
  }
  if (quad == 0) {
#pragma unroll
    for (int t = 0; t < 2; ++t) Lr[w][t][l15] = l_lane[t];
  }
  __syncthreads();
  const int tw = w & 1;                    // q-tile this wave would own (waves 0,1 write)
  float inv = 1.0f / (Lr[0][tw][l15] + Lr[1][tw][l15] + Lr[2][tw][l15] + Lr[3][tw][l15]);

  float* red = (float*)P32;
  u16* ob = attn_out + (size_t)(b * NQ_ + q0 + tw * 16 + l15) * INNER_ + h * 64;
#pragma unroll
  for (int d = 0; d < 4; ++d) {
    __syncthreads();
#pragma unroll
    for (int t = 0; t < 2; ++t)
      *(f32x4*)&red[(w * 2 + t) * 256 + quad * 64 + l15 * 4] = Oacc[d][t];
    __syncthreads();
    if (w < 2) {
      f32x4 r = *(const f32x4*)&red[(0 * 2 + w) * 256 + quad * 64 + l15 * 4];
#pragma unroll
      for (int ww = 1; ww < 4; ++ww) {
        f32x4 c = *(const f32x4*)&red[(ww * 2 + w) * 256 + quad * 64 + l15 * 4];
        r[0] += c[0]; r[1] += c[1]; r[2] += c[2]; r[3] += c[3];
      }
      *(u32*)(ob + d * 16 + quad * 4)     = pack2(r[0] * inv, r[1] * inv);
      *(u32*)(ob + d * 16 + quad * 4 + 2) = pack2(r[2] * inv, r[3] * inv);
    }
  }
}

// ---------------- driver ----------------
extern "C" void kernel_launch(void* const* d_in, const int* in_sizes, int n_in,
                              void* d_out, int out_size, void* d_ws, size_t ws_size,
                              hipStream_t stream) {
  const float* x    = (const float*)d_in[0];
  const float* ctx  = (const float*)d_in[1];
  const float* Wq   = (const float*)d_in[2];
  const float* Wkv  = (const float*)d_in[3];
  const float* Wout = (const float*)d_in[4];
  const float* bout = (const float*)d_in[5];

  char* ws = (char*)d_ws;
  u16* xb    = (u16*)(ws + (size_t)( 0u << 20));  // 4 MB  [dead after q_gemm]
  u16* ab    = (u16*)(ws + (size_t)( 0u << 20));  // 4 MB  [reuses xb]
  u16* ctxb  = (u16*)(ws + (size_t)( 4u << 20));  // 16 MB [dead after kv_gemm]
  u16* WqT   = (u16*)(ws + (size_t)(20u << 20));  // 2 MB
  u16* WkvT  = (u16*)(ws + (size_t)(22u << 20));  // 4 MB
  u16* WoutT = (u16*)(ws + (size_t)(26u << 20));  // 2 MB
  u16* qb    = (u16*)(ws + (size_t)(28u << 20));  // 4 MB
  u16* kb    = (u16*)(ws + (size_t)(32u << 20));  // 16 MB (K row-major bf16)
  u16* vTb   = (u16*)(ws + (size_t)(48u << 20));  // 16 MB (V transposed [bh*64+dh][NKV])

  // casts + weight transposes in one dispatch (fat cast blocks)
  prep<<<5376, 256, 0, stream>>>(x, ctx, Wq, Wkv, Wout, xb, ctxb, WqT, WkvT, WoutT);
  // q projection: 256 blocks, 64x128 tiles (full GPU)
  q_gemm<<<256, 256, 0, stream>>>(xb, WqT, qb);
  // kv projection: 256 blocks of 256x256, 8-phase pipelined, 1 block/CU
  kv_gemm<<<256, 512, 0, stream>>>(ctxb, WkvT, kb, vTb);
  // fused softmax attention: 1024 blocks (QBLK=32) x 256 threads, x=bh for XCD locality
  attn_kernel<<<dim3(32, 32), 256, 0, stream>>>(qb, kb, vTb, ab);
  // out = attn Wout + b_out : fp32, 256 blocks
  out_gemm<<<256, 256, 0, stream>>>(ab, WoutT, (float*)d_out, bout);
}

// Round 6
// 229.574 us; speedup vs baseline: 1.0652x; 1.0652x over previous
//
#include <hip/hip_runtime.h>
#include <stdint.h>

// Problem constants
#define B_    2
#define NQ_   1024
#define NKV_  4096
#define DQ_   1024
#define H_    16
#define DH_   64
#define INNER_ 1024

typedef unsigned short u16;
typedef uint32_t u32;
typedef __bf16 bf16x8 __attribute__((ext_vector_type(8)));
typedef float  f32x4  __attribute__((ext_vector_type(4)));

__device__ __forceinline__ u16 f2bf(float x) {           // RNE
  union { float f; uint32_t u; } v; v.f = x;
  uint32_t r = v.u + 0x7FFFu + ((v.u >> 16) & 1u);
  return (u16)(r >> 16);
}
__device__ __forceinline__ u32 pack2(float a, float b) { // RNE pair
  return (u32)f2bf(a) | ((u32)f2bf(b) << 16);
}
__device__ __forceinline__ u32 pack2rn(float a, float b) { // fast RN via v_perm (3 VALU)
  union { float f; u32 u; } x, y; x.f = a; y.f = b;
  return __builtin_amdgcn_perm(y.u + 0x8000u, x.u + 0x8000u, 0x07060302u);
}
__device__ __forceinline__ float bf2f(u16 s) {
  union { float f; uint32_t u; } v; v.u = ((uint32_t)s) << 16; return v.f;
}

// async global->LDS, 16B/lane; lds base wave-uniform, hw adds lane*16
__device__ __forceinline__ void gload16(const void* g, void* l) {
  __builtin_amdgcn_global_load_lds((const __attribute__((address_space(1))) void*)g,
                                   (__attribute__((address_space(3))) void*)l,
                                   16, 0, 0);
}

// ---------------- fused prep: casts + weight transposes in ONE dispatch -----------------
// blocks [0,1280): fat casts (8 x float4 per thread); [1280,2304): Wq^T;
// [2304,4352): Wkv^T; [4352,5376): Wout^T.
__global__ __launch_bounds__(256) void prep(const float* __restrict__ x,
                                            const float* __restrict__ ctx,
                                            const float* __restrict__ Wq,
                                            const float* __restrict__ Wkv,
                                            const float* __restrict__ Wout,
                                            u16* __restrict__ xb,
                                            u16* __restrict__ ctxb,
                                            u16* __restrict__ WqT,
                                            u16* __restrict__ WkvT,
                                            u16* __restrict__ WoutT) {
  int bid = blockIdx.x;
  if (bid < 1280) {                        // elementwise cast, 32 elems/thread
    const float* src; u16* dst; int fbase;  // float4 units
    if (bid < 256) { src = x;   dst = xb;   fbase = bid * 2048; }
    else           { src = ctx; dst = ctxb; fbase = (bid - 256) * 2048; }
#pragma unroll
    for (int u = 0; u < 8; ++u) {
      int i = (fbase + u * 256 + threadIdx.x) * 4;
      float4 v = *(const float4*)(src + i);
      uint2 o; o.x = pack2(v.x, v.y); o.y = pack2(v.z, v.w);
      *(uint2*)(dst + i) = o;
    }
    return;
  }
  // transpose+cast W[K][N] -> Wt[N][K]
  __shared__ float tile[32][33];
  const float* W; u16* Wt; int K, N, local, nsh;
  int b2 = bid - 1280;
  if (b2 < 1024)      { W = Wq;   Wt = WqT;   K = 1024; N = 1024; local = b2;        nsh = 5; }
  else if (b2 < 3072) { W = Wkv;  Wt = WkvT;  K = 1024; N = 2048; local = b2 - 1024; nsh = 6; }
  else                { W = Wout; Wt = WoutT; K = 1024; N = 1024; local = b2 - 3072; nsh = 5; }
  int n0 = (local & ((1 << nsh) - 1)) * 32;
  int k0 = (local >> nsh) * 32;
  int tx = threadIdx.x & 31, ty = threadIdx.x >> 5;   // 32 x 8
  for (int i = ty; i < 32; i += 8)
    tile[i][tx] = W[(size_t)(k0 + i) * N + n0 + tx];
  __syncthreads();
  for (int i = ty; i < 32; i += 8)
    Wt[(size_t)(n0 + i) * K + k0 + tx] = f2bf(tile[tx][i]);
}

// ---------------- kv projection: 256x256 / BK=64 / 8-wave 8-phase pipelined GEMM --------
// Round-1 proven (main loop + epilogues). K row-major; V transposed scatter.
__global__ __launch_bounds__(512, 2) void kv_gemm(const u16* __restrict__ ctxb,
                                                  const u16* __restrict__ WkvT,
                                                  u16* __restrict__ kb,
                                                  u16* __restrict__ vTb) {
  __shared__ __align__(16) u16 As[2][256 * 64];   // 64 KiB
  __shared__ __align__(16) u16 Bs[2][256 * 64];   // 64 KiB
  const int tid = threadIdx.x;
  const int lane = tid & 63;
  const int w = tid >> 6;                 // 0..7
  const int wr = w >> 2, wc = w & 3;      // 2 x 4 waves -> wave panel 128M x 64N
  const int l15 = lane & 15, quad = lane >> 4;
  const int K = 1024;

  // XCD-chunked bijective swizzle: each XCD gets 4 contiguous M-strips x all 8 N-tiles
  int bid = blockIdx.x;
  int wgid = (bid & 7) * 32 + (bid >> 3);
  const int tm = wgid >> 3, tn = wgid & 7;
  const int m0 = tm * 256, n0 = tn * 256;
  const u16* Ag = ctxb + (size_t)m0 * K;
  const u16* Bg = WkvT + (size_t)n0 * K;

  // per-thread stage source offsets (u16 units): row-reorder + chunk XOR pre-swizzle
  size_t offA[2][2], offB[2][2];          // [half][pass] - all uses const-indexed
#pragma unroll
  for (int ah = 0; ah < 2; ++ah)
#pragma unroll
    for (int p = 0; p < 2; ++p) {
      int c = p * 512 + (w << 6) + lane;  // chunk id within 16 KiB region
      int s = ah * 128 + (c >> 3);        // LDS slot (reordered row)
      int col = ((c & 7) ^ (s & 7)) << 3; // pre-swizzled source column (bf16)
      int rA = ((s >> 6) & 1) * 128 + ((s >> 7) & 1) * 64 + (s & 63);
      int rB = ((s >> 5) & 3) * 64 + ((s >> 7) & 1) * 32 + (s & 31);
      offA[ah][p] = (size_t)rA * 1024 + col;
      offB[ah][p] = (size_t)rB * 1024 + col;
    }

#define STAGE_A(bufi, ah, kk) do { \
    gload16(Ag + offA[ah][0] + (kk), &As[bufi][(ah) * 8192 + (w << 9)]); \
    gload16(Ag + offA[ah][1] + (kk), &As[bufi][(ah) * 8192 + 4096 + (w << 9)]); \
  } while (0)
#define STAGE_B(bufi, bh, kk) do { \
    gload16(Bg + offB[bh][0] + (kk), &Bs[bufi][(bh) * 8192 + (w << 9)]); \
    gload16(Bg + offB[bh][1] + (kk), &Bs[bufi][(bh) * 8192 + 4096 + (w << 9)]); \
  } while (0)
#define LDA2(dst, i8, bufi) do { \
    const int _s = ((i8) >> 2) * 128 + wr * 64 + ((i8) & 3) * 16 + l15; \
    const u16* _p = &As[bufi][_s * 64]; const int _x = _s & 7; \
    dst[0] = *(const bf16x8*)&_p[(quad ^ _x) << 3]; \
    dst[1] = *(const bf16x8*)&_p[((quad + 4) ^ _x) << 3]; \
  } while (0)
#define LDB2(dst, j, bufi) do { \
    const int _s = ((j) >> 1) * 128 + wc * 32 + ((j) & 1) * 16 + l15; \
    const u16* _p = &Bs[bufi][_s * 64]; const int _x = _s & 7; \
    dst[0] = *(const bf16x8*)&_p[(quad ^ _x) << 3]; \
    dst[1] = *(const bf16x8*)&_p[((quad + 4) ^ _x) << 3]; \
  } while (0)
#define MF(i0, j0, bb) do { \
    _Pragma("unroll") \
    for (int _i = 0; _i < 4; ++_i) { \
      acc[(i0) + _i][(j0)    ] = __builtin_amdgcn_mfma_f32_16x16x32_bf16(a[_i][0], bb[0][0], acc[(i0) + _i][(j0)    ], 0, 0, 0); \
      acc[(i0) + _i][(j0)    ] = __builtin_amdgcn_mfma_f32_16x16x32_bf16(a[_i][1], bb[0][1], acc[(i0) + _i][(j0)    ], 0, 0, 0); \
      acc[(i0) + _i][(j0) + 1] = __builtin_amdgcn_mfma_f32_16x16x32_bf16(a[_i][0], bb[1][0], acc[(i0) + _i][(j0) + 1], 0, 0, 0); \
      acc[(i0) + _i][(j0) + 1] = __builtin_amdgcn_mfma_f32_16x16x32_bf16(a[_i][1], bb[1][1], acc[(i0) + _i][(j0) + 1], 0, 0, 0); \
    } \
  } while (0)

  f32x4 acc[8][4] = {};
  bf16x8 a[4][2], b[2][2], c2[2][2];

  // prologue: full tile 0 into buf 0; queue = [Aa, Ba, Bb, Ab]
  STAGE_A(0, 0, 0);
  STAGE_B(0, 0, 0);
  STAGE_B(0, 1, 0);
  STAGE_A(0, 1, 0);
  asm volatile("s_waitcnt vmcnt(4)" ::: "memory");   // Aa,Ba ready
  __builtin_amdgcn_s_barrier();

#define KTILE(cur, nxt, kk, STG, W1, W2) do { \
    /* ph1: quadrant (ih0, jh0); reads Aa+Ba regions */ \
    LDB2(b[0], 0, cur); LDB2(b[1], 1, cur); \
    LDA2(a[0], 0, cur); LDA2(a[1], 1, cur); LDA2(a[2], 2, cur); LDA2(a[3], 3, cur); \
    if (STG) STAGE_A(nxt, 0, kk); \
    __builtin_amdgcn_s_barrier(); \
    asm volatile("s_waitcnt lgkmcnt(0)" ::: "memory"); \
    __builtin_amdgcn_s_setprio(1); MF(0, 0, b); __builtin_amdgcn_s_setprio(0); \
    asm volatile("s_waitcnt " W1 ::: "memory"); \
    __builtin_amdgcn_s_barrier(); \
    /* ph2: (ih0, jh1); reads Bb region */ \
    LDB2(c2[0], 2, cur); LDB2(c2[1], 3, cur); \
    if (STG) STAGE_B(nxt, 0, kk); \
    __builtin_amdgcn_s_barrier(); \
    asm volatile("s_waitcnt lgkmcnt(0)" ::: "memory"); \
    __builtin_amdgcn_s_setprio(1); MF(0, 2, c2); __builtin_amdgcn_s_setprio(0); \
    asm volatile("s_waitcnt " W2 ::: "memory"); \
    __builtin_amdgcn_s_barrier(); \
    /* ph3: (ih1, jh0); reads Ab region */ \
    LDA2(a[0], 4, cur); LDA2(a[1], 5, cur); LDA2(a[2], 6, cur); LDA2(a[3], 7, cur); \
    if (STG) STAGE_B(nxt, 1, kk); \
    __builtin_amdgcn_s_barrier(); \
    asm volatile("s_waitcnt lgkmcnt(0)" ::: "memory"); \
    __builtin_amdgcn_s_setprio(1); MF(4, 0, b); __builtin_amdgcn_s_setprio(0); \
    __builtin_amdgcn_s_barrier(); \
    /* ph4: (ih1, jh1); no ds_read */ \
    if (STG) STAGE_A(nxt, 1, kk); \
    __builtin_amdgcn_s_barrier(); \
    __builtin_amdgcn_s_setprio(1); MF(4, 2, c2); __builtin_amdgcn_s_setprio(0); \
    if (STG) { asm volatile("s_waitcnt vmcnt(4)" ::: "memory"); } \
    __builtin_amdgcn_s_barrier(); \
  } while (0)

  for (int T = 0; T < 15; ++T) {
    const int cur = T & 1, nxt = cur ^ 1, kk = (T + 1) * 64;
    KTILE(cur, nxt, kk, 1, "vmcnt(4)", "vmcnt(4)");
  }
  KTILE(1, 0, 0, 0, "vmcnt(2)", "vmcnt(0)");   // tail: nothing staged

  // epilogue (round-1 proven): tn<4 -> K row-major, tn>=4 -> V transposed scatter
  if (tn < 4) {
#pragma unroll
    for (int i8 = 0; i8 < 8; ++i8)
#pragma unroll
      for (int j = 0; j < 4; ++j) {
        int col = n0 + wc * 64 + j * 16 + l15;
#pragma unroll
        for (int r = 0; r < 4; ++r) {
          int row = m0 + wr * 128 + i8 * 16 + quad * 4 + r;
          kb[(size_t)row * 1024 + col] = f2bf(acc[i8][j][r]);
        }
      }
  } else {
    const int bb_ = m0 >> 12;
#pragma unroll
    for (int i8 = 0; i8 < 8; ++i8) {
      int kvr = (m0 & 4095) + wr * 128 + i8 * 16 + quad * 4;
#pragma unroll
      for (int j = 0; j < 4; ++j) {
        int c = (n0 - 1024) + wc * 64 + j * 16 + l15;
        int h = c >> 6, dh = c & 63;
        uint2 st;
        st.x = pack2(acc[i8][j][0], acc[i8][j][1]);
        st.y = pack2(acc[i8][j][2], acc[i8][j][3]);
        *(uint2*)&vTb[((size_t)((bb_ * 16 + h) * 64 + dh)) * NKV_ + kvr] = st;
      }
    }
  }
#undef STAGE_A
#undef STAGE_B
#undef LDA2
#undef LDB2
#undef MF
#undef KTILE
}

// ---------------- q projection: 64x128 tiles -> 256 blocks (full GPU), bf16 out ---------
__global__ __launch_bounds__(256) void q_gemm(const u16* __restrict__ A,
                                              const u16* __restrict__ Bt,
                                              u16* __restrict__ outp) {
  __shared__ __align__(16) u16 As[64 * 32];    // 4 KB
  __shared__ __align__(16) u16 Bs[128 * 32];   // 8 KB
  const int tid = threadIdx.x;
  const int lane = tid & 63;
  const int w = tid >> 6;
  const int wr = w >> 1, wc = w & 1;           // wave covers 32M x 64N
  const int l15 = lane & 15, quad = lane >> 4;
  const int unit = blockIdx.x;
  const int m0 = (unit >> 3) * 64, n0 = (unit & 7) * 128;
  const int K = 1024, N = 1024;

  const u16* Ab = A + (size_t)m0 * K;
  const u16* Bb = Bt + (size_t)n0 * K;
  f32x4 acc[2][4] = {};

  const int ar = tid >> 2, ac = (tid & 3) << 3;          // A: 256 chunks, 1/thread
  const int q1 = w * 64 + lane, q2 = q1 + 256;           // B: 512 chunks, 2/thread
  const int br1 = q1 >> 2, bc1 = (q1 & 3) << 3;
  const int br2 = q2 >> 2, bc2 = (q2 & 3) << 3;

  for (int k0 = 0; k0 < K; k0 += 32) {
    __syncthreads();
    gload16(Ab + (size_t)ar * K + k0 + ac, &As[w * 512]);
    gload16(Bb + (size_t)br1 * K + k0 + bc1, &Bs[w * 512]);
    gload16(Bb + (size_t)br2 * K + k0 + bc2, &Bs[2048 + w * 512]);
    __syncthreads();
    bf16x8 af[2], bfr[4];
#pragma unroll
    for (int i = 0; i < 2; ++i)
      af[i] = *(const bf16x8*)&As[(wr * 32 + i * 16 + l15) * 32 + quad * 8];
#pragma unroll
    for (int j = 0; j < 4; ++j)
      bfr[j] = *(const bf16x8*)&Bs[(wc * 64 + j * 16 + l15) * 32 + quad * 8];
#pragma unroll
    for (int i = 0; i < 2; ++i)
#pragma unroll
      for (int j = 0; j < 4; ++j)
        acc[i][j] = __builtin_amdgcn_mfma_f32_16x16x32_bf16(af[i], bfr[j], acc[i][j], 0, 0, 0);
  }

#pragma unroll
  for (int i = 0; i < 2; ++i)
#pragma unroll
    for (int j = 0; j < 4; ++j) {
      int col = n0 + wc * 64 + j * 16 + l15;
#pragma unroll
      for (int r = 0; r < 4; ++r) {
        int row = m0 + wr * 32 + i * 16 + quad * 4 + r;
        outp[(size_t)row * N + col] = f2bf(acc[i][j][r]);
      }
    }
}

// ---------------- out-proj GEMM: 64x128 tiles -> 256 blocks (full GPU) ------------------
__global__ __launch_bounds__(256) void out_gemm(const u16* __restrict__ A,
                                                const u16* __restrict__ Bt,
                                                float* __restrict__ Cout,
                                                const float* __restrict__ bias) {
  __shared__ __align__(16) u16 As[64 * 32];    // 4 KB
  __shared__ __align__(16) u16 Bs[128 * 32];   // 8 KB
  const int tid = threadIdx.x;
  const int lane = tid & 63;
  const int w = tid >> 6;
  const int wr = w >> 1, wc = w & 1;           // wave covers 32M x 64N
  const int l15 = lane & 15, quad = lane >> 4;
  const int unit = blockIdx.x;
  const int m0 = (unit >> 3) * 64, n0 = (unit & 7) * 128;
  const int K = 1024, N = 1024;

  const u16* Ab = A + (size_t)m0 * K;
  const u16* Bb = Bt + (size_t)n0 * K;
  f32x4 acc[2][4] = {};

  const int ar = tid >> 2, ac = (tid & 3) << 3;          // A: 256 chunks, 1/thread
  const int q1 = w * 64 + lane, q2 = q1 + 256;           // B: 512 chunks, 2/thread
  const int br1 = q1 >> 2, bc1 = (q1 & 3) << 3;
  const int br2 = q2 >> 2, bc2 = (q2 & 3) << 3;

  for (int k0 = 0; k0 < K; k0 += 32) {
    __syncthreads();
    gload16(Ab + (size_t)ar * K + k0 + ac, &As[w * 512]);
    gload16(Bb + (size_t)br1 * K + k0 + bc1, &Bs[w * 512]);
    gload16(Bb + (size_t)br2 * K + k0 + bc2, &Bs[2048 + w * 512]);
    __syncthreads();
    bf16x8 af[2], bfr[4];
#pragma unroll
    for (int i = 0; i < 2; ++i)
      af[i] = *(const bf16x8*)&As[(wr * 32 + i * 16 + l15) * 32 + quad * 8];
#pragma unroll
    for (int j = 0; j < 4; ++j)
      bfr[j] = *(const bf16x8*)&Bs[(wc * 64 + j * 16 + l15) * 32 + quad * 8];
#pragma unroll
    for (int i = 0; i < 2; ++i)
#pragma unroll
      for (int j = 0; j < 4; ++j)
        acc[i][j] = __builtin_amdgcn_mfma_f32_16x16x32_bf16(af[i], bfr[j], acc[i][j], 0, 0, 0);
  }

#pragma unroll
  for (int i = 0; i < 2; ++i)
#pragma unroll
    for (int j = 0; j < 4; ++j) {
      int col = n0 + wc * 64 + j * 16 + l15;
      float bv = bias[col];
#pragma unroll
      for (int r = 0; r < 4; ++r) {
        int row = m0 + wr * 32 + i * 16 + quad * 4 + r;
        Cout[(size_t)row * N + col] = acc[i][j][r] + bv;
      }
    }
}

// ---------------- flash attention: QBLK=128, 8 waves, traffic-halved --------------------
// R1/R4-proven staging+swizzle, re-partitioned to halve the K/V->LDS re-read traffic
// (the measured bottleneck: R4->R5 showed time ~ traffic at ~21 TB/s marginal).
// Block = 128 q-rows x one (b,h); 512 thr / 8 waves = 2kv-groups x 4q-groups.
// Per wave: kv-slice 64 (kvt=4), q-tile 32 (t=2) -> 16 QK + 16 PV MFMA/iter (unchanged
// per-wave density). Grid 256 blocks = 1/CU, 8 waves/CU (same TLP as R4's 2x4-wave).
// Total staged traffic: 256 blk x 32 it x 32KB = 256 MB (was 512). LDS ~70 KB.
__global__ __launch_bounds__(512, 2) void attn_kernel(const u16* __restrict__ qg,
                                                      const u16* __restrict__ kb,
                                                      const u16* __restrict__ vT,
                                                      u16* __restrict__ attn_out) {
  __shared__ __align__(16) u16 Ks[128 * 64];       // [kv][dh], 16B groups XOR-swizzled
  __shared__ __align__(16) u16 Vs[64 * 128];       // [dh][kv], XOR-swizzled (16 groups/row)
  __shared__ __align__(16) u32 P32[8 * 2 * 16 * 36]; // [w][t][q=l15][36] wave-private; 36 KB
  __shared__ float Lr[8][2][16];                   // [w][t][q] partial l

  const int tid = threadIdx.x;
  const int lane = tid & 63;
  const int w = tid >> 6;                  // 0..7
  const int wq = w & 3, wk = w >> 2;       // 4 q-groups x 2 kv-groups
  const int l15 = lane & 15, quad = lane >> 4;
  const int bh = blockIdx.x, b = bh >> 4, h = bh & 15;
  const int q0 = blockIdx.y * 128 + wq * 32;

  const float SC = 0.125f * 1.44269504088896340736f;   // dh^-0.5 * log2(e)
  union { u16 s[8]; bf16x8 v; } qf[2][2];
#pragma unroll
  for (int t = 0; t < 2; ++t)
#pragma unroll
    for (int kc = 0; kc < 2; ++kc) {
      const u16* qp = qg + (size_t)(b * NQ_ + q0 + t * 16 + l15) * INNER_ + h * 64 +
                      kc * 32 + quad * 8;
      union { u16 s[8]; uint4 u; } tmp;
      tmp.u = *(const uint4*)qp;
#pragma unroll
      for (int e = 0; e < 8; ++e) qf[t][kc].s[e] = f2bf(bf2f(tmp.s[e]) * SC);
    }

  // staging: 512 threads, 2 passes each for K (1024 chunks) and V (1024 chunks);
  // chunk-id formulas identical to the proven 4x256 version.
#define STAGEKV(j0) do { \
    _Pragma("unroll") \
    for (int i_ = 0; i_ < 2; ++i_) { \
      int s_ = i_ * 512 + tid; \
      int kr = s_ >> 3, kg = (s_ ^ kr) & 7; \
      gload16(kb + (size_t)(b * NKV_ + (j0) + kr) * 1024 + h * 64 + kg * 8, \
              &Ks[(i_ * 512 + w * 64) * 8]); \
      int vr = s_ >> 4, vg = (s_ ^ vr) & 15; \
      gload16(vT + (size_t)(bh * 64 + vr) * NKV_ + (j0) + vg * 8, \
              &Vs[(i_ * 512 + w * 64) * 8]); \
    } \
  } while (0)

  f32x4 Oacc[4][2] = {};
  float l_lane[2] = {0.f, 0.f};

  STAGEKV(0);                                // prologue: tile 0

  for (int it = 0; it < 32; ++it) {
    __syncthreads();                         // tile `it` staged

    // fragment reads for tile `it`: this wave's kv slice = wk*64 .. +64
    bf16x8 kf[4][2];
#pragma unroll
    for (int kvt = 0; kvt < 4; ++kvt)
#pragma unroll
      for (int kc = 0; kc < 2; ++kc)
        kf[kvt][kc] = *(const bf16x8*)
          &Ks[(wk * 64 + kvt * 16 + l15) * 64 + (((kc * 4 + quad) ^ l15) & 7) * 8];
    bf16x8 vf[4][2];                         // [d][kh]: V[dh=d*16+l15][kv=wk*64+kh*32+quad*8+e]
#pragma unroll
    for (int d = 0; d < 4; ++d)
#pragma unroll
      for (int kh = 0; kh < 2; ++kh)
        vf[d][kh] = *(const bf16x8*)
          &Vs[(d * 16 + l15) * 128 + (((wk * 8 + kh * 4 + quad) ^ l15) & 15) * 8];

    __syncthreads();                         // all waves done reading Ks/Vs

    if (it < 31) STAGEKV((it + 1) * 128);    // overwrite: overlaps compute below

    // QK + softmax per kvt (sacc transient)
#pragma unroll
    for (int kvt = 0; kvt < 4; ++kvt) {
      f32x4 sacc[2] = {};
      __builtin_amdgcn_s_setprio(1);
#pragma unroll
      for (int t = 0; t < 2; ++t) {
        sacc[t] = __builtin_amdgcn_mfma_f32_16x16x32_bf16(kf[kvt][0], qf[t][0].v, sacc[t], 0, 0, 0);
        sacc[t] = __builtin_amdgcn_mfma_f32_16x16x32_bf16(kf[kvt][1], qf[t][1].v, sacc[t], 0, 0, 0);
      }
      __builtin_amdgcn_s_setprio(0);
#pragma unroll
      for (int t = 0; t < 2; ++t) {
        float p0 = __builtin_amdgcn_exp2f(sacc[t][0]);
        float p1 = __builtin_amdgcn_exp2f(sacc[t][1]);
        float p2 = __builtin_amdgcn_exp2f(sacc[t][2]);
        float p3 = __builtin_amdgcn_exp2f(sacc[t][3]);
        l_lane[t] += (p0 + p1) + (p2 + p3);
        uint2 pk; pk.x = pack2rn(p0, p1); pk.y = pack2rn(p2, p3);
        *(uint2*)&P32[((w * 2 + t) * 16 + l15) * 36 + kvt * 8 + quad * 2] = pk;
      }
    }

    // PV: pf[t][kh] = P[q=l15][kv = wk-slice, kh*32 + quad*8+e] from wave-private LDS
    bf16x8 pf[2][2];
#pragma unroll
    for (int t = 0; t < 2; ++t)
#pragma unroll
      for (int kh = 0; kh < 2; ++kh)
        pf[t][kh] = *(const bf16x8*)&P32[((w * 2 + t) * 16 + l15) * 36 + kh * 16 + quad * 4];
    __builtin_amdgcn_s_setprio(1);
#pragma unroll
    for (int d = 0; d < 4; ++d)
#pragma unroll
      for (int t = 0; t < 2; ++t) {
        Oacc[d][t] = __builtin_amdgcn_mfma_f32_16x16x32_bf16(vf[d][0], pf[t][0], Oacc[d][t], 0, 0, 0);
        Oacc[d][t] = __builtin_amdgcn_mfma_f32_16x16x32_bf16(vf[d][1], pf[t][1], Oacc[d][t], 0, 0, 0);
      }
    __builtin_amdgcn_s_setprio(0);
  }
#undef STAGEKV

  // l: reduce over quad groups (this wave's 64 kv), publish per wave
#pragma unroll
  for (int t = 0; t < 2; ++t) {
    l_lane[t] += __shfl_xor(l_lane[t], 16);
    l_lane[t] += __shfl_xor(l_lane[t], 32);
  }
  if (quad == 0) {
#pragma unroll
    for (int t = 0; t < 2; ++t) Lr[w][t][l15] = l_lane[t];
  }
  __syncthreads();                           // Lr ready; P32 free for reuse

  // cross-wave (wk pair) O reduce via LDS (reuse P32: need 32 KB <= 36 KB)
  float* RedF = (float*)P32;
  if (wk == 1) {
#pragma unroll
    for (int d = 0; d < 4; ++d)
#pragma unroll
      for (int t = 0; t < 2; ++t)
        *(f32x4*)&RedF[(((w & 3) * 4 + d) * 2 + t) * 256 + lane * 4] = Oacc[d][t];
  }
  __syncthreads();
  if (wk == 0) {
#pragma unroll
    for (int t = 0; t < 2; ++t) {
      float inv = 1.0f / (Lr[w][t][l15] + Lr[w + 4][t][l15]);
      u16* ob = attn_out + (size_t)(b * NQ_ + q0 + t * 16 + l15) * INNER_ + h * 64;
#pragma unroll
      for (int d = 0; d < 4; ++d) {
        f32x4 r = Oacc[d][t];
        f32x4 c = *(const f32x4*)&RedF[((w * 4 + d) * 2 + t) * 256 + lane * 4];
        r[0] += c[0]; r[1] += c[1]; r[2] += c[2]; r[3] += c[3];
        *(u32*)(ob + d * 16 + quad * 4)     = pack2(r[0] * inv, r[1] * inv);
        *(u32*)(ob + d * 16 + quad * 4 + 2) = pack2(r[2] * inv, r[3] * inv);
      }
    }
  }
}

// ---------------- driver ----------------
extern "C" void kernel_launch(void* const* d_in, const int* in_sizes, int n_in,
                              void* d_out, int out_size, void* d_ws, size_t ws_size,
                              hipStream_t stream) {
  const float* x    = (const float*)d_in[0];
  const float* ctx  = (const float*)d_in[1];
  const float* Wq   = (const float*)d_in[2];
  const float* Wkv  = (const float*)d_in[3];
  const float* Wout = (const float*)d_in[4];
  const float* bout = (const float*)d_in[5];

  char* ws = (char*)d_ws;
  u16* xb    = (u16*)(ws + (size_t)( 0u << 20));  // 4 MB  [dead after q_gemm]
  u16* ab    = (u16*)(ws + (size_t)( 0u << 20));  // 4 MB  [reuses xb]
  u16* ctxb  = (u16*)(ws + (size_t)( 4u << 20));  // 16 MB [dead after kv_gemm]
  u16* WqT   = (u16*)(ws + (size_t)(20u << 20));  // 2 MB
  u16* WkvT  = (u16*)(ws + (size_t)(22u << 20));  // 4 MB
  u16* WoutT = (u16*)(ws + (size_t)(26u << 20));  // 2 MB
  u16* qb    = (u16*)(ws + (size_t)(28u << 20));  // 4 MB
  u16* kb    = (u16*)(ws + (size_t)(32u << 20));  // 16 MB (K row-major bf16)
  u16* vTb   = (u16*)(ws + (size_t)(48u << 20));  // 16 MB (V transposed [bh*64+dh][NKV])

  // casts + weight transposes in one dispatch (fat cast blocks)
  prep<<<5376, 256, 0, stream>>>(x, ctx, Wq, Wkv, Wout, xb, ctxb, WqT, WkvT, WoutT);
  // q projection: 256 blocks, 64x128 tiles (full GPU)
  q_gemm<<<256, 256, 0, stream>>>(xb, WqT, qb);
  // kv projection: 256 blocks of 256x256, 8-phase pipelined, 1 block/CU
  kv_gemm<<<256, 512, 0, stream>>>(ctxb, WkvT, kb, vTb);
  // fused softmax attention: 256 blocks (QBLK=128) x 512 threads, x=bh for XCD locality
  attn_kernel<<<dim3(32, 8), 512, 0, stream>>>(qb, kb, vTb, ab);
  // out = attn Wout + b_out : fp32, 256 blocks
  out_gemm<<<256, 256, 0, stream>>>(ab, WoutT, (float*)d_out, bout);
}

// Round 7
// 226.458 us; speedup vs baseline: 1.0798x; 1.0138x over previous
//
#include <hip/hip_runtime.h>
#include <stdint.h>

// Problem constants
#define B_    2
#define NQ_   1024
#define NKV_  4096
#define DQ_   1024
#define H_    16
#define DH_   64
#define INNER_ 1024

typedef unsigned short u16;
typedef uint32_t u32;
typedef __bf16 bf16x8 __attribute__((ext_vector_type(8)));
typedef float  f32x4  __attribute__((ext_vector_type(4)));

__device__ __forceinline__ u16 f2bf(float x) {           // RNE
  union { float f; uint32_t u; } v; v.f = x;
  uint32_t r = v.u + 0x7FFFu + ((v.u >> 16) & 1u);
  return (u16)(r >> 16);
}
__device__ __forceinline__ u32 pack2(float a, float b) { // RNE pair
  return (u32)f2bf(a) | ((u32)f2bf(b) << 16);
}
__device__ __forceinline__ u32 cvtpk(float lo, float hi) { // 1-VALU packed cvt (RNE)
  u32 r;
  asm("v_cvt_pk_bf16_f32 %0, %1, %2" : "=v"(r) : "v"(lo), "v"(hi));
  return r;
}
__device__ __forceinline__ float bf2f(u16 s) {
  union { float f; uint32_t u; } v; v.u = ((uint32_t)s) << 16; return v.f;
}

// async global->LDS, 16B/lane; lds base wave-uniform, hw adds lane*16
__device__ __forceinline__ void gload16(const void* g, void* l) {
  __builtin_amdgcn_global_load_lds((const __attribute__((address_space(1))) void*)g,
                                   (__attribute__((address_space(3))) void*)l,
                                   16, 0, 0);
}

// ---------------- fused prep: casts + weight transposes in ONE dispatch -----------------
__global__ __launch_bounds__(256) void prep(const float* __restrict__ x,
                                            const float* __restrict__ ctx,
                                            const float* __restrict__ Wq,
                                            const float* __restrict__ Wkv,
                                            const float* __restrict__ Wout,
                                            u16* __restrict__ xb,
                                            u16* __restrict__ ctxb,
                                            u16* __restrict__ WqT,
                                            u16* __restrict__ WkvT,
                                            u16* __restrict__ WoutT) {
  int bid = blockIdx.x;
  if (bid < 1280) {                        // elementwise cast, 32 elems/thread
    const float* src; u16* dst; int fbase;  // float4 units
    if (bid < 256) { src = x;   dst = xb;   fbase = bid * 2048; }
    else           { src = ctx; dst = ctxb; fbase = (bid - 256) * 2048; }
#pragma unroll
    for (int u = 0; u < 8; ++u) {
      int i = (fbase + u * 256 + threadIdx.x) * 4;
      float4 v = *(const float4*)(src + i);
      uint2 o; o.x = pack2(v.x, v.y); o.y = pack2(v.z, v.w);
      *(uint2*)(dst + i) = o;
    }
    return;
  }
  // transpose+cast W[K][N] -> Wt[N][K]
  __shared__ float tile[32][33];
  const float* W; u16* Wt; int K, N, local, nsh;
  int b2 = bid - 1280;
  if (b2 < 1024)      { W = Wq;   Wt = WqT;   K = 1024; N = 1024; local = b2;        nsh = 5; }
  else if (b2 < 3072) { W = Wkv;  Wt = WkvT;  K = 1024; N = 2048; local = b2 - 1024; nsh = 6; }
  else                { W = Wout; Wt = WoutT; K = 1024; N = 1024; local = b2 - 3072; nsh = 5; }
  int n0 = (local & ((1 << nsh) - 1)) * 32;
  int k0 = (local >> nsh) * 32;
  int tx = threadIdx.x & 31, ty = threadIdx.x >> 5;   // 32 x 8
  for (int i = ty; i < 32; i += 8)
    tile[i][tx] = W[(size_t)(k0 + i) * N + n0 + tx];
  __syncthreads();
  for (int i = ty; i < 32; i += 8)
    Wt[(size_t)(n0 + i) * K + k0 + tx] = f2bf(tile[tx][i]);
}

// ---------------- kv projection: 256x256 / BK=64 / 8-wave 8-phase pipelined GEMM --------
// Main loop round-1 proven. Epilogues emit K/V in FRAGMENT-IMAGE layouts:
//   region(bh, it, w_attn) = ((bh*32+it)*4 + w_attn) * 2048 u16 (4 KB contiguous)
//   K image [32 rows][8 groups of 16B], group swizzled: elem (kv,dh) stored at
//     rl=kv&31(within wave slice), g0=(dh>>3)^(rl&7), e=dh&7 -> rl*64 + g0*8 + e
//   V image [64 dh][32 kv] linear: dh*32 + kv32
// attn then stages each wave's K/V slice as 8 contiguous 1KB global_load_lds.
__global__ __launch_bounds__(512, 2) void kv_gemm(const u16* __restrict__ ctxb,
                                                  const u16* __restrict__ WkvT,
                                                  u16* __restrict__ kb,
                                                  u16* __restrict__ vTb) {
  __shared__ __align__(16) u16 As[2][256 * 64];   // 64 KiB
  __shared__ __align__(16) u16 Bs[2][256 * 64];   // 64 KiB
  const int tid = threadIdx.x;
  const int lane = tid & 63;
  const int w = tid >> 6;                 // 0..7
  const int wr = w >> 2, wc = w & 3;      // 2 x 4 waves -> wave panel 128M x 64N
  const int l15 = lane & 15, quad = lane >> 4;
  const int K = 1024;

  // XCD-chunked bijective swizzle
  int bid = blockIdx.x;
  int wgid = (bid & 7) * 32 + (bid >> 3);
  const int tm = wgid >> 3, tn = wgid & 7;
  const int m0 = tm * 256, n0 = tn * 256;
  const u16* Ag = ctxb + (size_t)m0 * K;
  const u16* Bg = WkvT + (size_t)n0 * K;

  size_t offA[2][2], offB[2][2];
#pragma unroll
  for (int ah = 0; ah < 2; ++ah)
#pragma unroll
    for (int p = 0; p < 2; ++p) {
      int c = p * 512 + (w << 6) + lane;  // chunk id within 16 KiB region
      int s = ah * 128 + (c >> 3);        // LDS slot (reordered row)
      int col = ((c & 7) ^ (s & 7)) << 3; // pre-swizzled source column (bf16)
      int rA = ((s >> 6) & 1) * 128 + ((s >> 7) & 1) * 64 + (s & 63);
      int rB = ((s >> 5) & 3) * 64 + ((s >> 7) & 1) * 32 + (s & 31);
      offA[ah][p] = (size_t)rA * 1024 + col;
      offB[ah][p] = (size_t)rB * 1024 + col;
    }

#define STAGE_A(bufi, ah, kk) do { \
    gload16(Ag + offA[ah][0] + (kk), &As[bufi][(ah) * 8192 + (w << 9)]); \
    gload16(Ag + offA[ah][1] + (kk), &As[bufi][(ah) * 8192 + 4096 + (w << 9)]); \
  } while (0)
#define STAGE_B(bufi, bh, kk) do { \
    gload16(Bg + offB[bh][0] + (kk), &Bs[bufi][(bh) * 8192 + (w << 9)]); \
    gload16(Bg + offB[bh][1] + (kk), &Bs[bufi][(bh) * 8192 + 4096 + (w << 9)]); \
  } while (0)
#define LDA2(dst, i8, bufi) do { \
    const int _s = ((i8) >> 2) * 128 + wr * 64 + ((i8) & 3) * 16 + l15; \
    const u16* _p = &As[bufi][_s * 64]; const int _x = _s & 7; \
    dst[0] = *(const bf16x8*)&_p[(quad ^ _x) << 3]; \
    dst[1] = *(const bf16x8*)&_p[((quad + 4) ^ _x) << 3]; \
  } while (0)
#define LDB2(dst, j, bufi) do { \
    const int _s = ((j) >> 1) * 128 + wc * 32 + ((j) & 1) * 16 + l15; \
    const u16* _p = &Bs[bufi][_s * 64]; const int _x = _s & 7; \
    dst[0] = *(const bf16x8*)&_p[(quad ^ _x) << 3]; \
    dst[1] = *(const bf16x8*)&_p[((quad + 4) ^ _x) << 3]; \
  } while (0)
#define MF(i0, j0, bb) do { \
    _Pragma("unroll") \
    for (int _i = 0; _i < 4; ++_i) { \
      acc[(i0) + _i][(j0)    ] = __builtin_amdgcn_mfma_f32_16x16x32_bf16(a[_i][0], bb[0][0], acc[(i0) + _i][(j0)    ], 0, 0, 0); \
      acc[(i0) + _i][(j0)    ] = __builtin_amdgcn_mfma_f32_16x16x32_bf16(a[_i][1], bb[0][1], acc[(i0) + _i][(j0)    ], 0, 0, 0); \
      acc[(i0) + _i][(j0) + 1] = __builtin_amdgcn_mfma_f32_16x16x32_bf16(a[_i][0], bb[1][0], acc[(i0) + _i][(j0) + 1], 0, 0, 0); \
      acc[(i0) + _i][(j0) + 1] = __builtin_amdgcn_mfma_f32_16x16x32_bf16(a[_i][1], bb[1][1], acc[(i0) + _i][(j0) + 1], 0, 0, 0); \
    } \
  } while (0)

  f32x4 acc[8][4] = {};
  bf16x8 a[4][2], b[2][2], c2[2][2];

  STAGE_A(0, 0, 0);
  STAGE_B(0, 0, 0);
  STAGE_B(0, 1, 0);
  STAGE_A(0, 1, 0);
  asm volatile("s_waitcnt vmcnt(4)" ::: "memory");
  __builtin_amdgcn_s_barrier();

#define KTILE(cur, nxt, kk, STG, W1, W2) do { \
    LDB2(b[0], 0, cur); LDB2(b[1], 1, cur); \
    LDA2(a[0], 0, cur); LDA2(a[1], 1, cur); LDA2(a[2], 2, cur); LDA2(a[3], 3, cur); \
    if (STG) STAGE_A(nxt, 0, kk); \
    __builtin_amdgcn_s_barrier(); \
    asm volatile("s_waitcnt lgkmcnt(0)" ::: "memory"); \
    __builtin_amdgcn_s_setprio(1); MF(0, 0, b); __builtin_amdgcn_s_setprio(0); \
    asm volatile("s_waitcnt " W1 ::: "memory"); \
    __builtin_amdgcn_s_barrier(); \
    LDB2(c2[0], 2, cur); LDB2(c2[1], 3, cur); \
    if (STG) STAGE_B(nxt, 0, kk); \
    __builtin_amdgcn_s_barrier(); \
    asm volatile("s_waitcnt lgkmcnt(0)" ::: "memory"); \
    __builtin_amdgcn_s_setprio(1); MF(0, 2, c2); __builtin_amdgcn_s_setprio(0); \
    asm volatile("s_waitcnt " W2 ::: "memory"); \
    __builtin_amdgcn_s_barrier(); \
    LDA2(a[0], 4, cur); LDA2(a[1], 5, cur); LDA2(a[2], 6, cur); LDA2(a[3], 7, cur); \
    if (STG) STAGE_B(nxt, 1, kk); \
    __builtin_amdgcn_s_barrier(); \
    asm volatile("s_waitcnt lgkmcnt(0)" ::: "memory"); \
    __builtin_amdgcn_s_setprio(1); MF(4, 0, b); __builtin_amdgcn_s_setprio(0); \
    __builtin_amdgcn_s_barrier(); \
    if (STG) STAGE_A(nxt, 1, kk); \
    __builtin_amdgcn_s_barrier(); \
    __builtin_amdgcn_s_setprio(1); MF(4, 2, c2); __builtin_amdgcn_s_setprio(0); \
    if (STG) { asm volatile("s_waitcnt vmcnt(4)" ::: "memory"); } \
    __builtin_amdgcn_s_barrier(); \
  } while (0)

  for (int T = 0; T < 15; ++T) {
    const int cur = T & 1, nxt = cur ^ 1, kk = (T + 1) * 64;
    KTILE(cur, nxt, kk, 1, "vmcnt(4)", "vmcnt(4)");
  }
  KTILE(1, 0, 0, 0, "vmcnt(2)", "vmcnt(0)");   // tail: nothing staged

  // ---- epilogues: fragment-image layouts ----
  if (tn < 4) {
    // K image: region + rl*64 + ((gd^rl)&7)*8 + e
    const int b_ = m0 >> 12;
    const int h_ = (n0 >> 6) + wc;
    const int bh_ = b_ * 16 + h_;
    const int it0 = ((m0 & 4095) >> 7) + wr;
    const int e = l15 & 7;
#pragma unroll
    for (int i8 = 0; i8 < 8; ++i8) {
      const size_t reg_ = ((size_t)(bh_ * 32 + it0) * 4 + (i8 >> 1)) * 2048;
#pragma unroll
      for (int j = 0; j < 4; ++j) {
        const int gd = j * 2 + (l15 >> 3);
#pragma unroll
        for (int r = 0; r < 4; ++r) {
          const int rl = (i8 & 1) * 16 + quad * 4 + r;
          kb[reg_ + rl * 64 + ((gd ^ rl) & 7) * 8 + e] = f2bf(acc[i8][j][r]);
        }
      }
    }
  } else {
    // V image: region + dh*32 + kv32 (uint2 = 4 consecutive kv)
    const int b_ = m0 >> 12;
    const int h_ = ((n0 - 1024) >> 6) + wc;
    const int bh_ = b_ * 16 + h_;
    const int it0 = ((m0 & 4095) >> 7) + wr;
#pragma unroll
    for (int i8 = 0; i8 < 8; ++i8) {
      const size_t reg_ = ((size_t)(bh_ * 32 + it0) * 4 + (i8 >> 1)) * 2048;
#pragma unroll
      for (int j = 0; j < 4; ++j) {
        uint2 st;
        st.x = pack2(acc[i8][j][0], acc[i8][j][1]);
        st.y = pack2(acc[i8][j][2], acc[i8][j][3]);
        *(uint2*)&vTb[reg_ + (size_t)(j * 16 + l15) * 32 + (i8 & 1) * 16 + quad * 4] = st;
      }
    }
  }
#undef STAGE_A
#undef STAGE_B
#undef LDA2
#undef LDB2
#undef MF
#undef KTILE
}

// ---------------- q projection: 64x128 tiles -> 256 blocks (full GPU), bf16 out ---------
__global__ __launch_bounds__(256) void q_gemm(const u16* __restrict__ A,
                                              const u16* __restrict__ Bt,
                                              u16* __restrict__ outp) {
  __shared__ __align__(16) u16 As[64 * 32];    // 4 KB
  __shared__ __align__(16) u16 Bs[128 * 32];   // 8 KB
  const int tid = threadIdx.x;
  const int lane = tid & 63;
  const int w = tid >> 6;
  const int wr = w >> 1, wc = w & 1;
  const int l15 = lane & 15, quad = lane >> 4;
  const int unit = blockIdx.x;
  const int m0 = (unit >> 3) * 64, n0 = (unit & 7) * 128;
  const int K = 1024, N = 1024;

  const u16* Ab = A + (size_t)m0 * K;
  const u16* Bb = Bt + (size_t)n0 * K;
  f32x4 acc[2][4] = {};

  const int ar = tid >> 2, ac = (tid & 3) << 3;
  const int q1 = w * 64 + lane, q2 = q1 + 256;
  const int br1 = q1 >> 2, bc1 = (q1 & 3) << 3;
  const int br2 = q2 >> 2, bc2 = (q2 & 3) << 3;

  for (int k0 = 0; k0 < K; k0 += 32) {
    __syncthreads();
    gload16(Ab + (size_t)ar * K + k0 + ac, &As[w * 512]);
    gload16(Bb + (size_t)br1 * K + k0 + bc1, &Bs[w * 512]);
    gload16(Bb + (size_t)br2 * K + k0 + bc2, &Bs[2048 + w * 512]);
    __syncthreads();
    bf16x8 af[2], bfr[4];
#pragma unroll
    for (int i = 0; i < 2; ++i)
      af[i] = *(const bf16x8*)&As[(wr * 32 + i * 16 + l15) * 32 + quad * 8];
#pragma unroll
    for (int j = 0; j < 4; ++j)
      bfr[j] = *(const bf16x8*)&Bs[(wc * 64 + j * 16 + l15) * 32 + quad * 8];
#pragma unroll
    for (int i = 0; i < 2; ++i)
#pragma unroll
      for (int j = 0; j < 4; ++j)
        acc[i][j] = __builtin_amdgcn_mfma_f32_16x16x32_bf16(af[i], bfr[j], acc[i][j], 0, 0, 0);
  }

#pragma unroll
  for (int i = 0; i < 2; ++i)
#pragma unroll
    for (int j = 0; j < 4; ++j) {
      int col = n0 + wc * 64 + j * 16 + l15;
#pragma unroll
      for (int r = 0; r < 4; ++r) {
        int row = m0 + wr * 32 + i * 16 + quad * 4 + r;
        outp[(size_t)row * N + col] = f2bf(acc[i][j][r]);
      }
    }
}

// ---------------- out-proj GEMM: 64x128 tiles -> 256 blocks (full GPU) ------------------
__global__ __launch_bounds__(256) void out_gemm(const u16* __restrict__ A,
                                                const u16* __restrict__ Bt,
                                                float* __restrict__ Cout,
                                                const float* __restrict__ bias) {
  __shared__ __align__(16) u16 As[64 * 32];    // 4 KB
  __shared__ __align__(16) u16 Bs[128 * 32];   // 8 KB
  const int tid = threadIdx.x;
  const int lane = tid & 63;
  const int w = tid >> 6;
  const int wr = w >> 1, wc = w & 1;
  const int l15 = lane & 15, quad = lane >> 4;
  const int unit = blockIdx.x;
  const int m0 = (unit >> 3) * 64, n0 = (unit & 7) * 128;
  const int K = 1024, N = 1024;

  const u16* Ab = A + (size_t)m0 * K;
  const u16* Bb = Bt + (size_t)n0 * K;
  f32x4 acc[2][4] = {};

  const int ar = tid >> 2, ac = (tid & 3) << 3;
  const int q1 = w * 64 + lane, q2 = q1 + 256;
  const int br1 = q1 >> 2, bc1 = (q1 & 3) << 3;
  const int br2 = q2 >> 2, bc2 = (q2 & 3) << 3;

  for (int k0 = 0; k0 < K; k0 += 32) {
    __syncthreads();
    gload16(Ab + (size_t)ar * K + k0 + ac, &As[w * 512]);
    gload16(Bb + (size_t)br1 * K + k0 + bc1, &Bs[w * 512]);
    gload16(Bb + (size_t)br2 * K + k0 + bc2, &Bs[2048 + w * 512]);
    __syncthreads();
    bf16x8 af[2], bfr[4];
#pragma unroll
    for (int i = 0; i < 2; ++i)
      af[i] = *(const bf16x8*)&As[(wr * 32 + i * 16 + l15) * 32 + quad * 8];
#pragma unroll
    for (int j = 0; j < 4; ++j)
      bfr[j] = *(const bf16x8*)&Bs[(wc * 64 + j * 16 + l15) * 32 + quad * 8];
#pragma unroll
    for (int i = 0; i < 2; ++i)
#pragma unroll
      for (int j = 0; j < 4; ++j)
        acc[i][j] = __builtin_amdgcn_mfma_f32_16x16x32_bf16(af[i], bfr[j], acc[i][j], 0, 0, 0);
  }

#pragma unroll
  for (int i = 0; i < 2; ++i)
#pragma unroll
    for (int j = 0; j < 4; ++j) {
      int col = n0 + wc * 64 + j * 16 + l15;
      float bv = bias[col];
#pragma unroll
      for (int r = 0; r < 4; ++r) {
        int row = m0 + wr * 32 + i * 16 + quad * 4 + r;
        Cout[(size_t)row * N + col] = acc[i][j][r] + bv;
      }
    }
}

// ---------------- flash attention: BARRIER-FREE wave-private pipeline -------------------
// Each wave owns kv slice [w*32, w*32+32) (no cross-wave sharing, proven by the R1/R4
// layout). Wave stages its OWN 8 KB K/V fragment-image slice (8 contiguous 1KB
// global_load_lds), double-buffered, synchronized by per-wave counted vmcnt(8) — ZERO
// __syncthreads in the 32-iter loop. Waves free-run and self-stagger so MFMA/VALU/LDS
// phases of different waves overlap (R1-R6 showed phase-locked serialization was the
// bottleneck). P round-trip eliminated: cvt_pk + v_permlane32_swap + shfl_xor(16)
// redistribute P into the PV B-fragment in registers (T12 analog; mapping lane-verified).
__global__ __launch_bounds__(256, 2) void attn_kernel(const u16* __restrict__ kimg_q,
                                                      const u16* __restrict__ kimg,
                                                      const u16* __restrict__ vimg,
                                                      u16* __restrict__ attn_out) {
  __shared__ __align__(16) u16 KV[4][2][4096];   // [wave][buf][K 2048 | V 2048] = 64 KB
  __shared__ float Lr[4][4][16];                 // [w][t][q] partial l

  const u16* qg = kimg_q;
  const int tid = threadIdx.x;
  const int lane = tid & 63;
  const int w = tid >> 6;
  const int l15 = lane & 15, quad = lane >> 4;
  const int bh = blockIdx.x, b = bh >> 4, h = bh & 15;
  const int q0 = blockIdx.y * 64;

  const float SC = 0.125f * 1.44269504088896340736f;   // dh^-0.5 * log2(e)
  union { u16 s[8]; bf16x8 v; } qf[4][2];
#pragma unroll
  for (int t = 0; t < 4; ++t)
#pragma unroll
    for (int kc = 0; kc < 2; ++kc) {
      const u16* qp = qg + (size_t)(b * NQ_ + q0 + t * 16 + l15) * INNER_ + h * 64 +
                      kc * 32 + quad * 8;
      union { u16 s[8]; uint4 u; } tmp;
      tmp.u = *(const uint4*)qp;
#pragma unroll
      for (int e = 0; e < 8; ++e) qf[t][kc].s[e] = f2bf(bf2f(tmp.s[e]) * SC);
    }

  // per-wave fragment-image bases (region stride per it = 4 waves * 2048 u16)
  const u16* kg = kimg + ((size_t)(bh * 32) * 4 + w) * 2048 + lane * 8;
  const u16* vg = vimg + ((size_t)(bh * 32) * 4 + w) * 2048 + lane * 8;

#define STAGE(bf, itv) do { \
    const size_t _o = (size_t)(itv) * 8192; \
    gload16(kg + _o,        &KV[w][bf][0]); \
    gload16(kg + _o + 512,  &KV[w][bf][512]); \
    gload16(kg + _o + 1024, &KV[w][bf][1024]); \
    gload16(kg + _o + 1536, &KV[w][bf][1536]); \
    gload16(vg + _o,        &KV[w][bf][2048]); \
    gload16(vg + _o + 512,  &KV[w][bf][2560]); \
    gload16(vg + _o + 1024, &KV[w][bf][3072]); \
    gload16(vg + _o + 1536, &KV[w][bf][3584]); \
  } while (0)

  f32x4 Oacc[4][4] = {};
  float l_lane[4] = {0.f, 0.f, 0.f, 0.f};

  STAGE(0, 0);

  for (int it = 0; it < 32; ++it) {
    const int bf = it & 1;
    if (it < 31) {
      STAGE(bf ^ 1, it + 1);                       // 8 newer loads in flight
      asm volatile("s_waitcnt vmcnt(8)" ::: "memory");   // buf bf complete
    } else {
      asm volatile("s_waitcnt vmcnt(0)" ::: "memory");
    }

    // wave-private fragment reads (K XOR-swizzled rows, V linear)
    bf16x8 kf[2][2], vf[4];
#pragma unroll
    for (int kvt = 0; kvt < 2; ++kvt)
#pragma unroll
      for (int kc = 0; kc < 2; ++kc)
        kf[kvt][kc] = *(const bf16x8*)
          &KV[w][bf][(kvt * 16 + l15) * 64 + (((kc * 4 + quad) ^ l15) & 7) * 8];
#pragma unroll
    for (int d = 0; d < 4; ++d)
      vf[d] = *(const bf16x8*)&KV[w][bf][2048 + (d * 16 + l15) * 32 + quad * 8];

    // QK^T
    f32x4 sacc[2][4] = {};
    __builtin_amdgcn_s_setprio(1);
#pragma unroll
    for (int kvt = 0; kvt < 2; ++kvt)
#pragma unroll
      for (int t = 0; t < 4; ++t) {
        sacc[kvt][t] = __builtin_amdgcn_mfma_f32_16x16x32_bf16(
            kf[kvt][0], qf[t][0].v, sacc[kvt][t], 0, 0, 0);
        sacc[kvt][t] = __builtin_amdgcn_mfma_f32_16x16x32_bf16(
            kf[kvt][1], qf[t][1].v, sacc[kvt][t], 0, 0, 0);
      }
    __builtin_amdgcn_s_setprio(0);

    // softmax + in-register P redistribution into PV B-fragments
    bf16x8 pf[4];
#pragma unroll
    for (int t = 0; t < 4; ++t) {
      float p0 = __builtin_amdgcn_exp2f(sacc[0][t][0]);
      float p1 = __builtin_amdgcn_exp2f(sacc[0][t][1]);
      float p2 = __builtin_amdgcn_exp2f(sacc[0][t][2]);
      float p3 = __builtin_amdgcn_exp2f(sacc[0][t][3]);
      float p4 = __builtin_amdgcn_exp2f(sacc[1][t][0]);
      float p5 = __builtin_amdgcn_exp2f(sacc[1][t][1]);
      float p6 = __builtin_amdgcn_exp2f(sacc[1][t][2]);
      float p7 = __builtin_amdgcn_exp2f(sacc[1][t][3]);
      l_lane[t] += ((p0 + p1) + (p2 + p3)) + ((p4 + p5) + (p6 + p7));
      u32 A0 = cvtpk(p0, p1), A1 = cvtpk(p2, p3);   // kvt0: kv {4q,4q+1}, {4q+2,4q+3}
      u32 B0 = cvtpk(p4, p5), B1 = cvtpk(p6, p7);   // kvt1
      // swap: A0 -> [A0@q0,A0@q1,B0@q0,B0@q1], B0 -> [A0@q2,A0@q3,B0@q2,B0@q3]
      asm("v_permlane32_swap_b32 %0, %1" : "+v"(A0), "+v"(B0));
      asm("v_permlane32_swap_b32 %0, %1" : "+v"(A1), "+v"(B1));
      u32 sx16 = (u32)__shfl_xor((int)A0, 16);
      u32 sy16 = (u32)__shfl_xor((int)B0, 16);
      u32 tx16 = (u32)__shfl_xor((int)A1, 16);
      u32 ty16 = (u32)__shfl_xor((int)B1, 16);
      const bool odd = (quad & 1);
      union { u32 u[4]; bf16x8 v; } pk_;
      pk_.u[0] = odd ? sy16 : A0;    // kv {8Q+0,1}
      pk_.u[1] = odd ? ty16 : A1;    // kv {8Q+2,3}
      pk_.u[2] = odd ? B0   : sx16;  // kv {8Q+4,5}
      pk_.u[3] = odd ? B1   : tx16;  // kv {8Q+6,7}
      pf[t] = pk_.v;
    }

    // PV
    __builtin_amdgcn_s_setprio(1);
#pragma unroll
    for (int d = 0; d < 4; ++d)
#pragma unroll
      for (int t = 0; t < 4; ++t)
        Oacc[d][t] = __builtin_amdgcn_mfma_f32_16x16x32_bf16(vf[d], pf[t], Oacc[d][t],
                                                             0, 0, 0);
    __builtin_amdgcn_s_setprio(0);
  }
#undef STAGE

#pragma unroll
  for (int t = 0; t < 4; ++t) {
    l_lane[t] += __shfl_xor(l_lane[t], 16);
    l_lane[t] += __shfl_xor(l_lane[t], 32);
  }
  if (quad == 0) {
#pragma unroll
    for (int t = 0; t < 4; ++t) Lr[w][t][l15] = l_lane[t];
  }
  __syncthreads();                    // also fences all waves' main loops
  float inv = 1.0f / (Lr[0][w][l15] + Lr[1][w][l15] + Lr[2][w][l15] + Lr[3][w][l15]);

  float* red = (float*)&KV[0][0][0];  // reuse staging LDS (needs 16 KB)
  u16* ob = attn_out + (size_t)(b * NQ_ + q0 + w * 16 + l15) * INNER_ + h * 64;
#pragma unroll
  for (int d = 0; d < 4; ++d) {
    __syncthreads();
#pragma unroll
    for (int t = 0; t < 4; ++t)
      *(f32x4*)&red[(w * 4 + t) * 256 + quad * 64 + l15 * 4] = Oacc[d][t];
    __syncthreads();
    f32x4 r = *(const f32x4*)&red[(0 * 4 + w) * 256 + quad * 64 + l15 * 4];
#pragma unroll
    for (int ww = 1; ww < 4; ++ww) {
      f32x4 c = *(const f32x4*)&red[(ww * 4 + w) * 256 + quad * 64 + l15 * 4];
      r[0] += c[0]; r[1] += c[1]; r[2] += c[2]; r[3] += c[3];
    }
    *(u32*)(ob + d * 16 + quad * 4)     = pack2(r[0] * inv, r[1] * inv);
    *(u32*)(ob + d * 16 + quad * 4 + 2) = pack2(r[2] * inv, r[3] * inv);
  }
}

// ---------------- driver ----------------
extern "C" void kernel_launch(void* const* d_in, const int* in_sizes, int n_in,
                              void* d_out, int out_size, void* d_ws, size_t ws_size,
                              hipStream_t stream) {
  const float* x    = (const float*)d_in[0];
  const float* ctx  = (const float*)d_in[1];
  const float* Wq   = (const float*)d_in[2];
  const float* Wkv  = (const float*)d_in[3];
  const float* Wout = (const float*)d_in[4];
  const float* bout = (const float*)d_in[5];

  char* ws = (char*)d_ws;
  u16* xb    = (u16*)(ws + (size_t)( 0u << 20));  // 4 MB  [dead after q_gemm]
  u16* ab    = (u16*)(ws + (size_t)( 0u << 20));  // 4 MB  [reuses xb]
  u16* ctxb  = (u16*)(ws + (size_t)( 4u << 20));  // 16 MB [dead after kv_gemm]
  u16* WqT   = (u16*)(ws + (size_t)(20u << 20));  // 2 MB
  u16* WkvT  = (u16*)(ws + (size_t)(22u << 20));  // 4 MB
  u16* WoutT = (u16*)(ws + (size_t)(26u << 20));  // 2 MB
  u16* qb    = (u16*)(ws + (size_t)(28u << 20));  // 4 MB
  u16* kb    = (u16*)(ws + (size_t)(32u << 20));  // 16 MB (K fragment-image)
  u16* vTb   = (u16*)(ws + (size_t)(48u << 20));  // 16 MB (V fragment-image)

  // casts + weight transposes in one dispatch (fat cast blocks)
  prep<<<5376, 256, 0, stream>>>(x, ctx, Wq, Wkv, Wout, xb, ctxb, WqT, WkvT, WoutT);
  // q projection: 256 blocks, 64x128 tiles (full GPU)
  q_gemm<<<256, 256, 0, stream>>>(xb, WqT, qb);
  // kv projection: 256 blocks of 256x256, 8-phase pipelined, 1 block/CU
  kv_gemm<<<256, 512, 0, stream>>>(ctxb, WkvT, kb, vTb);
  // fused softmax attention: 512 blocks x 256 threads, barrier-free wave pipeline
  attn_kernel<<<dim3(32, 16), 256, 0, stream>>>(qb, kb, vTb, ab);
  // out = attn Wout + b_out : fp32, 256 blocks
  out_gemm<<<256, 256, 0, stream>>>(ab, WoutT, (float*)d_out, bout);
}

// Round 8
// 221.530 us; speedup vs baseline: 1.1038x; 1.0222x over previous
//
#include <hip/hip_runtime.h>
#include <stdint.h>

// Problem constants
#define B_    2
#define NQ_   1024
#define NKV_  4096
#define DQ_   1024
#define H_    16
#define DH_   64
#define INNER_ 1024

typedef unsigned short u16;
typedef uint32_t u32;
typedef __bf16 bf16x8 __attribute__((ext_vector_type(8)));
typedef float  f32x4  __attribute__((ext_vector_type(4)));

__device__ __forceinline__ u16 f2bf(float x) {           // RNE
  union { float f; uint32_t u; } v; v.f = x;
  uint32_t r = v.u + 0x7FFFu + ((v.u >> 16) & 1u);
  return (u16)(r >> 16);
}
__device__ __forceinline__ u32 pack2(float a, float b) { // RNE pair
  return (u32)f2bf(a) | ((u32)f2bf(b) << 16);
}
__device__ __forceinline__ u32 pack2rn(float a, float b) { // fast RN via v_perm (3 VALU)
  union { float f; u32 u; } x, y; x.f = a; y.f = b;
  return __builtin_amdgcn_perm(y.u + 0x8000u, x.u + 0x8000u, 0x07060302u);
}
__device__ __forceinline__ float bf2f(u16 s) {
  union { float f; uint32_t u; } v; v.u = ((uint32_t)s) << 16; return v.f;
}

// async global->LDS, 16B/lane; lds base wave-uniform, hw adds lane*16
__device__ __forceinline__ void gload16(const void* g, void* l) {
  __builtin_amdgcn_global_load_lds((const __attribute__((address_space(1))) void*)g,
                                   (__attribute__((address_space(3))) void*)l,
                                   16, 0, 0);
}

// ---------------- fused prep: casts + weight transposes in ONE dispatch -----------------
// blocks [0,1280): fat casts (8 x float4 per thread); [1280,2304): Wq^T;
// [2304,4352): Wkv^T; [4352,5376): Wout^T.
__global__ __launch_bounds__(256) void prep(const float* __restrict__ x,
                                            const float* __restrict__ ctx,
                                            const float* __restrict__ Wq,
                                            const float* __restrict__ Wkv,
                                            const float* __restrict__ Wout,
                                            u16* __restrict__ xb,
                                            u16* __restrict__ ctxb,
                                            u16* __restrict__ WqT,
                                            u16* __restrict__ WkvT,
                                            u16* __restrict__ WoutT) {
  int bid = blockIdx.x;
  if (bid < 1280) {                        // elementwise cast, 32 elems/thread
    const float* src; u16* dst; int fbase;  // float4 units
    if (bid < 256) { src = x;   dst = xb;   fbase = bid * 2048; }
    else           { src = ctx; dst = ctxb; fbase = (bid - 256) * 2048; }
#pragma unroll
    for (int u = 0; u < 8; ++u) {
      int i = (fbase + u * 256 + threadIdx.x) * 4;
      float4 v = *(const float4*)(src + i);
      uint2 o; o.x = pack2(v.x, v.y); o.y = pack2(v.z, v.w);
      *(uint2*)(dst + i) = o;
    }
    return;
  }
  // transpose+cast W[K][N] -> Wt[N][K]
  __shared__ float tile[32][33];
  const float* W; u16* Wt; int K, N, local, nsh;
  int b2 = bid - 1280;
  if (b2 < 1024)      { W = Wq;   Wt = WqT;   K = 1024; N = 1024; local = b2;        nsh = 5; }
  else if (b2 < 3072) { W = Wkv;  Wt = WkvT;  K = 1024; N = 2048; local = b2 - 1024; nsh = 6; }
  else                { W = Wout; Wt = WoutT; K = 1024; N = 1024; local = b2 - 3072; nsh = 5; }
  int n0 = (local & ((1 << nsh) - 1)) * 32;
  int k0 = (local >> nsh) * 32;
  int tx = threadIdx.x & 31, ty = threadIdx.x >> 5;   // 32 x 8
  for (int i = ty; i < 32; i += 8)
    tile[i][tx] = W[(size_t)(k0 + i) * N + n0 + tx];
  __syncthreads();
  for (int i = ty; i < 32; i += 8)
    Wt[(size_t)(n0 + i) * K + k0 + tx] = f2bf(tile[tx][i]);
}

// ---------------- kv projection: 256x256 / BK=64 / FAITHFUL 8-phase schedule ------------
// 2 K-steps per iteration (buf0=even step, buf1=odd step). Per phase:
// {ds_read quadrant ; stage 1 half-tile (2x gload_lds) ; barrier ; lgkmcnt(0) ;
//  setprio(1) 16 MFMA setprio(0) ; [vmcnt(6) at ph4/ph8 ONLY] ; barrier}.
// Stage ledger (iter i): ph1:Ab(2i+1)  ph2:Aa(2i+2) ph3:Ba(2i+2) ph4:Bb(2i+2)
//                        ph5:Ab(2i+2)  ph6:Aa(2i+3) ph7:Ba(2i+3) ph8:Bb(2i+3)
// Every staged region died >=1 barrier-pair earlier (WAR-safe); every vmcnt(6)'s
// targets are >=4 phases old (latency covered). Prologue: 14 loads + vmcnt(6).
// Tail iter: stage only ph1 (Ab of last step); vmcnt(0)@ph4.
// LDS layout / swizzle / epilogues byte-identical to the R1-proven kernel.
__global__ __launch_bounds__(512, 2) void kv_gemm(const u16* __restrict__ ctxb,
                                                  const u16* __restrict__ WkvT,
                                                  u16* __restrict__ kb,
                                                  u16* __restrict__ vTb) {
  __shared__ __align__(16) u16 As[2][256 * 64];   // 64 KiB
  __shared__ __align__(16) u16 Bs[2][256 * 64];   // 64 KiB
  const int tid = threadIdx.x;
  const int lane = tid & 63;
  const int w = tid >> 6;                 // 0..7
  const int wr = w >> 2, wc = w & 3;      // 2 x 4 waves -> wave panel 128M x 64N
  const int l15 = lane & 15, quad = lane >> 4;
  const int K = 1024;

  // XCD-chunked bijective swizzle
  int bid = blockIdx.x;
  int wgid = (bid & 7) * 32 + (bid >> 3);
  const int tm = wgid >> 3, tn = wgid & 7;
  const int m0 = tm * 256, n0 = tn * 256;
  const u16* Ag = ctxb + (size_t)m0 * K;
  const u16* Bg = WkvT + (size_t)n0 * K;

  // per-thread stage source offsets (u16 units): row-reorder + chunk XOR pre-swizzle
  size_t offA[2][2], offB[2][2];
#pragma unroll
  for (int ah = 0; ah < 2; ++ah)
#pragma unroll
    for (int p = 0; p < 2; ++p) {
      int c = p * 512 + (w << 6) + lane;  // chunk id within 16 KiB region
      int s = ah * 128 + (c >> 3);        // LDS slot (reordered row)
      int col = ((c & 7) ^ (s & 7)) << 3; // pre-swizzled source column (bf16)
      int rA = ((s >> 6) & 1) * 128 + ((s >> 7) & 1) * 64 + (s & 63);
      int rB = ((s >> 5) & 3) * 64 + ((s >> 7) & 1) * 32 + (s & 31);
      offA[ah][p] = (size_t)rA * 1024 + col;
      offB[ah][p] = (size_t)rB * 1024 + col;
    }

#define STAGE_A(bufi, ah, kk) do { \
    gload16(Ag + offA[ah][0] + (kk), &As[bufi][(ah) * 8192 + (w << 9)]); \
    gload16(Ag + offA[ah][1] + (kk), &As[bufi][(ah) * 8192 + 4096 + (w << 9)]); \
  } while (0)
#define STAGE_B(bufi, bh, kk) do { \
    gload16(Bg + offB[bh][0] + (kk), &Bs[bufi][(bh) * 8192 + (w << 9)]); \
    gload16(Bg + offB[bh][1] + (kk), &Bs[bufi][(bh) * 8192 + 4096 + (w << 9)]); \
  } while (0)
#define LDA2(dst, i8, bufi) do { \
    const int _s = ((i8) >> 2) * 128 + wr * 64 + ((i8) & 3) * 16 + l15; \
    const u16* _p = &As[bufi][_s * 64]; const int _x = _s & 7; \
    dst[0] = *(const bf16x8*)&_p[(quad ^ _x) << 3]; \
    dst[1] = *(const bf16x8*)&_p[((quad + 4) ^ _x) << 3]; \
  } while (0)
#define LDB2(dst, j, bufi) do { \
    const int _s = ((j) >> 1) * 128 + wc * 32 + ((j) & 1) * 16 + l15; \
    const u16* _p = &Bs[bufi][_s * 64]; const int _x = _s & 7; \
    dst[0] = *(const bf16x8*)&_p[(quad ^ _x) << 3]; \
    dst[1] = *(const bf16x8*)&_p[((quad + 4) ^ _x) << 3]; \
  } while (0)
#define MF(i0, j0, bb) do { \
    _Pragma("unroll") \
    for (int _i = 0; _i < 4; ++_i) { \
      acc[(i0) + _i][(j0)    ] = __builtin_amdgcn_mfma_f32_16x16x32_bf16(a[_i][0], bb[0][0], acc[(i0) + _i][(j0)    ], 0, 0, 0); \
      acc[(i0) + _i][(j0)    ] = __builtin_amdgcn_mfma_f32_16x16x32_bf16(a[_i][1], bb[0][1], acc[(i0) + _i][(j0)    ], 0, 0, 0); \
      acc[(i0) + _i][(j0) + 1] = __builtin_amdgcn_mfma_f32_16x16x32_bf16(a[_i][0], bb[1][0], acc[(i0) + _i][(j0) + 1], 0, 0, 0); \
      acc[(i0) + _i][(j0) + 1] = __builtin_amdgcn_mfma_f32_16x16x32_bf16(a[_i][1], bb[1][1], acc[(i0) + _i][(j0) + 1], 0, 0, 0); \
    } \
  } while (0)
#define BAR()   __builtin_amdgcn_s_barrier()
#define LGKM0() asm volatile("s_waitcnt lgkmcnt(0)" ::: "memory")

  f32x4 acc[8][4] = {};
  bf16x8 a[4][2], b[2][2], c2[2][2];

  // prologue: step0 full (Aa,Ba,Bb,Ab) + step1 trio (Aa,Ba,Bb) = 14 loads
  STAGE_A(0, 0, 0);
  STAGE_B(0, 0, 0);
  STAGE_B(0, 1, 0);
  STAGE_A(0, 1, 0);
  STAGE_A(1, 0, 64);
  STAGE_B(1, 0, 64);
  STAGE_B(1, 1, 64);
  asm volatile("s_waitcnt vmcnt(6)" ::: "memory");   // step0's 8 loads complete
  BAR();

  // one iteration = 128 K (steps at k2 and k2+64); STG=1 steady, STG=0 tail.
#define HALF(bufi, kAb, kNext, STG, WMID, WEND) do { \
    /* phA: quadrant (i8 0-3, j 0-1); stage Ab(this buf's CURRENT step+?) */ \
    LDB2(b[0], 0, bufi); LDB2(b[1], 1, bufi); \
    LDA2(a[0], 0, bufi); LDA2(a[1], 1, bufi); LDA2(a[2], 2, bufi); LDA2(a[3], 3, bufi); \
    if (kAb >= 0) STAGE_A((bufi) ^ 1, 1, kAb); \
    BAR(); LGKM0(); \
    __builtin_amdgcn_s_setprio(1); MF(0, 0, b); __builtin_amdgcn_s_setprio(0); \
    BAR(); \
    /* phB: quadrant (i8 0-3, j 2-3); stage Aa(next step into THIS buf) */ \
    LDB2(c2[0], 2, bufi); LDB2(c2[1], 3, bufi); \
    if (STG) STAGE_A(bufi, 0, kNext); \
    BAR(); LGKM0(); \
    __builtin_amdgcn_s_setprio(1); MF(0, 2, c2); __builtin_amdgcn_s_setprio(0); \
    BAR(); \
    /* phC: quadrant (i8 4-7, j 0-1); stage Ba(next) */ \
    LDA2(a[0], 4, bufi); LDA2(a[1], 5, bufi); LDA2(a[2], 6, bufi); LDA2(a[3], 7, bufi); \
    if (STG) STAGE_B(bufi, 0, kNext); \
    BAR(); LGKM0(); \
    __builtin_amdgcn_s_setprio(1); MF(4, 0, b); __builtin_amdgcn_s_setprio(0); \
    BAR(); \
    /* phD: quadrant (i8 4-7, j 2-3); stage Bb(next); counted wait */ \
    if (STG) STAGE_B(bufi, 1, kNext); \
    BAR(); \
    __builtin_amdgcn_s_setprio(1); MF(4, 2, c2); __builtin_amdgcn_s_setprio(0); \
    WMID; \
    BAR(); \
  } while (0)

  for (int i = 0; i < 7; ++i) {
    const int k2 = i * 128;
    // phases 1-4: buf0 (step 2i). ph1 stages Ab(step 2i+1)->buf1 @ k2+64.
    // ph2-4 stage Aa,Ba,Bb(step 2i+2)->buf0 @ k2+128. ph4: vmcnt(6).
    HALF(0, k2 + 64, k2 + 128, 1,
         asm volatile("s_waitcnt vmcnt(6)" ::: "memory"), );
    // phases 5-8: buf1 (step 2i+1). ph5 stages Ab(step 2i+2)->buf0 @ k2+128.
    // ph6-8 stage Aa,Ba,Bb(step 2i+3)->buf1 @ k2+192. ph8: vmcnt(6).
    HALF(1, k2 + 128, k2 + 192, 1,
         asm volatile("s_waitcnt vmcnt(6)" ::: "memory"), );
  }
  // tail iteration: steps 14 (k=896, buf0) and 15 (k=960, buf1).
  // ph1 stages Ab(step15)->buf1 @960; nothing else staged; vmcnt(0)@ph4.
  HALF(0, 960, 0, 0,
       asm volatile("s_waitcnt vmcnt(0)" ::: "memory"), );
  HALF(1, -1, 0, 0, , );

#undef HALF
#undef BAR
#undef LGKM0

  // epilogue (round-1 proven): tn<4 -> K row-major, tn>=4 -> V transposed scatter
  if (tn < 4) {
#pragma unroll
    for (int i8 = 0; i8 < 8; ++i8)
#pragma unroll
      for (int j = 0; j < 4; ++j) {
        int col = n0 + wc * 64 + j * 16 + l15;
#pragma unroll
        for (int r = 0; r < 4; ++r) {
          int row = m0 + wr * 128 + i8 * 16 + quad * 4 + r;
          kb[(size_t)row * 1024 + col] = f2bf(acc[i8][j][r]);
        }
      }
  } else {
    const int bb_ = m0 >> 12;
#pragma unroll
    for (int i8 = 0; i8 < 8; ++i8) {
      int kvr = (m0 & 4095) + wr * 128 + i8 * 16 + quad * 4;
#pragma unroll
      for (int j = 0; j < 4; ++j) {
        int c = (n0 - 1024) + wc * 64 + j * 16 + l15;
        int h = c >> 6, dh = c & 63;
        uint2 st;
        st.x = pack2(acc[i8][j][0], acc[i8][j][1]);
        st.y = pack2(acc[i8][j][2], acc[i8][j][3]);
        *(uint2*)&vTb[((size_t)((bb_ * 16 + h) * 64 + dh)) * NKV_ + kvr] = st;
      }
    }
  }
#undef STAGE_A
#undef STAGE_B
#undef LDA2
#undef LDB2
#undef MF
}

// ---------------- q projection: 64x128 tiles -> 256 blocks (full GPU), bf16 out ---------
__global__ __launch_bounds__(256) void q_gemm(const u16* __restrict__ A,
                                              const u16* __restrict__ Bt,
                                              u16* __restrict__ outp) {
  __shared__ __align__(16) u16 As[64 * 32];    // 4 KB
  __shared__ __align__(16) u16 Bs[128 * 32];   // 8 KB
  const int tid = threadIdx.x;
  const int lane = tid & 63;
  const int w = tid >> 6;
  const int wr = w >> 1, wc = w & 1;           // wave covers 32M x 64N
  const int l15 = lane & 15, quad = lane >> 4;
  const int unit = blockIdx.x;
  const int m0 = (unit >> 3) * 64, n0 = (unit & 7) * 128;
  const int K = 1024, N = 1024;

  const u16* Ab = A + (size_t)m0 * K;
  const u16* Bb = Bt + (size_t)n0 * K;
  f32x4 acc[2][4] = {};

  const int ar = tid >> 2, ac = (tid & 3) << 3;          // A: 256 chunks, 1/thread
  const int q1 = w * 64 + lane, q2 = q1 + 256;           // B: 512 chunks, 2/thread
  const int br1 = q1 >> 2, bc1 = (q1 & 3) << 3;
  const int br2 = q2 >> 2, bc2 = (q2 & 3) << 3;

  for (int k0 = 0; k0 < K; k0 += 32) {
    __syncthreads();
    gload16(Ab + (size_t)ar * K + k0 + ac, &As[w * 512]);
    gload16(Bb + (size_t)br1 * K + k0 + bc1, &Bs[w * 512]);
    gload16(Bb + (size_t)br2 * K + k0 + bc2, &Bs[2048 + w * 512]);
    __syncthreads();
    bf16x8 af[2], bfr[4];
#pragma unroll
    for (int i = 0; i < 2; ++i)
      af[i] = *(const bf16x8*)&As[(wr * 32 + i * 16 + l15) * 32 + quad * 8];
#pragma unroll
    for (int j = 0; j < 4; ++j)
      bfr[j] = *(const bf16x8*)&Bs[(wc * 64 + j * 16 + l15) * 32 + quad * 8];
#pragma unroll
    for (int i = 0; i < 2; ++i)
#pragma unroll
      for (int j = 0; j < 4; ++j)
        acc[i][j] = __builtin_amdgcn_mfma_f32_16x16x32_bf16(af[i], bfr[j], acc[i][j], 0, 0, 0);
  }

#pragma unroll
  for (int i = 0; i < 2; ++i)
#pragma unroll
    for (int j = 0; j < 4; ++j) {
      int col = n0 + wc * 64 + j * 16 + l15;
#pragma unroll
      for (int r = 0; r < 4; ++r) {
        int row = m0 + wr * 32 + i * 16 + quad * 4 + r;
        outp[(size_t)row * N + col] = f2bf(acc[i][j][r]);
      }
    }
}

// ---------------- out-proj GEMM: 64x128 tiles -> 256 blocks (full GPU) ------------------
__global__ __launch_bounds__(256) void out_gemm(const u16* __restrict__ A,
                                                const u16* __restrict__ Bt,
                                                float* __restrict__ Cout,
                                                const float* __restrict__ bias) {
  __shared__ __align__(16) u16 As[64 * 32];    // 4 KB
  __shared__ __align__(16) u16 Bs[128 * 32];   // 8 KB
  const int tid = threadIdx.x;
  const int lane = tid & 63;
  const int w = tid >> 6;
  const int wr = w >> 1, wc = w & 1;           // wave covers 32M x 64N
  const int l15 = lane & 15, quad = lane >> 4;
  const int unit = blockIdx.x;
  const int m0 = (unit >> 3) * 64, n0 = (unit & 7) * 128;
  const int K = 1024, N = 1024;

  const u16* Ab = A + (size_t)m0 * K;
  const u16* Bb = Bt + (size_t)n0 * K;
  f32x4 acc[2][4] = {};

  const int ar = tid >> 2, ac = (tid & 3) << 3;          // A: 256 chunks, 1/thread
  const int q1 = w * 64 + lane, q2 = q1 + 256;           // B: 512 chunks, 2/thread
  const int br1 = q1 >> 2, bc1 = (q1 & 3) << 3;
  const int br2 = q2 >> 2, bc2 = (q2 & 3) << 3;

  for (int k0 = 0; k0 < K; k0 += 32) {
    __syncthreads();
    gload16(Ab + (size_t)ar * K + k0 + ac, &As[w * 512]);
    gload16(Bb + (size_t)br1 * K + k0 + bc1, &Bs[w * 512]);
    gload16(Bb + (size_t)br2 * K + k0 + bc2, &Bs[2048 + w * 512]);
    __syncthreads();
    bf16x8 af[2], bfr[4];
#pragma unroll
    for (int i = 0; i < 2; ++i)
      af[i] = *(const bf16x8*)&As[(wr * 32 + i * 16 + l15) * 32 + quad * 8];
#pragma unroll
    for (int j = 0; j < 4; ++j)
      bfr[j] = *(const bf16x8*)&Bs[(wc * 64 + j * 16 + l15) * 32 + quad * 8];
#pragma unroll
    for (int i = 0; i < 2; ++i)
#pragma unroll
      for (int j = 0; j < 4; ++j)
        acc[i][j] = __builtin_amdgcn_mfma_f32_16x16x32_bf16(af[i], bfr[j], acc[i][j], 0, 0, 0);
  }

#pragma unroll
  for (int i = 0; i < 2; ++i)
#pragma unroll
    for (int j = 0; j < 4; ++j) {
      int col = n0 + wc * 64 + j * 16 + l15;
      float bv = bias[col];
#pragma unroll
      for (int r = 0; r < 4; ++r) {
        int row = m0 + wr * 32 + i * 16 + quad * 4 + r;
        Cout[(size_t)row * N + col] = acc[i][j][r] + bv;
      }
    }
}

// ---------------- flash attention: R4 exact (proven 56.8 us) ----------------------------
// LDS-staged K/V with XOR swizzle; per iter { ds_read fragments ; barrier ; STAGE(t+1) ;
// compute ; barrier }; stage latency hides under compute. QBLK=64, 4 waves, 2 blocks/CU.
__global__ __launch_bounds__(256, 2) void attn_kernel(const u16* __restrict__ qg,
                                                      const u16* __restrict__ kb,
                                                      const u16* __restrict__ vT,
                                                      u16* __restrict__ attn_out) {
  __shared__ __align__(16) u16 Ks[128 * 64];       // [kv][dh], 16B groups XOR-swizzled
  __shared__ __align__(16) u16 Vs[64 * 128];       // [dh][kv], XOR-swizzled (16 groups/row)
  __shared__ __align__(16) u32 P32[4 * 4 * 16 * 20]; // [w][t][q=l15][20]: wave-private pairs
  __shared__ float Lr[4][4][16];                   // [w][t][q] partial l

  const int tid = threadIdx.x;
  const int lane = tid & 63;
  const int w = tid >> 6;
  const int l15 = lane & 15, quad = lane >> 4;
  const int bh = blockIdx.x, b = bh >> 4, h = bh & 15;
  const int q0 = blockIdx.y * 64;

  const float SC = 0.125f * 1.44269504088896340736f;   // dh^-0.5 * log2(e)
  union { u16 s[8]; bf16x8 v; } qf[4][2];
#pragma unroll
  for (int t = 0; t < 4; ++t)
#pragma unroll
    for (int kc = 0; kc < 2; ++kc) {
      const u16* qp = qg + (size_t)(b * NQ_ + q0 + t * 16 + l15) * INNER_ + h * 64 +
                      kc * 32 + quad * 8;
      union { u16 s[8]; uint4 u; } tmp;
      tmp.u = *(const uint4*)qp;
#pragma unroll
      for (int e = 0; e < 8; ++e) qf[t][kc].s[e] = f2bf(bf2f(tmp.s[e]) * SC);
    }

#define STAGEKV(j0) do { \
    _Pragma("unroll") \
    for (int i_ = 0; i_ < 4; ++i_) { \
      int s_ = i_ * 256 + tid; \
      int kr = s_ >> 3, kg = (s_ ^ kr) & 7; \
      gload16(kb + (size_t)(b * NKV_ + (j0) + kr) * 1024 + h * 64 + kg * 8, \
              &Ks[(i_ * 256 + w * 64) * 8]); \
      int vr = s_ >> 4, vg = (s_ ^ vr) & 15; \
      gload16(vT + (size_t)(bh * 64 + vr) * NKV_ + (j0) + vg * 8, \
              &Vs[(i_ * 256 + w * 64) * 8]); \
    } \
  } while (0)

  f32x4 Oacc[4][4] = {};
  float l_lane[4] = {0.f, 0.f, 0.f, 0.f};

  STAGEKV(0);                                // prologue: tile 0

  for (int it = 0; it < 32; ++it) {
    __syncthreads();                         // tile `it` staged (vmcnt drained per-wave)

    // fragment reads for tile `it` (this wave's complete K/V consumption)
    bf16x8 kf[2][2];
#pragma unroll
    for (int kvt = 0; kvt < 2; ++kvt)
#pragma unroll
      for (int kc = 0; kc < 2; ++kc)
        kf[kvt][kc] = *(const bf16x8*)
          &Ks[(w * 32 + kvt * 16 + l15) * 64 + (((kc * 4 + quad) ^ l15) & 7) * 8];
    bf16x8 vf[4];
#pragma unroll
    for (int d = 0; d < 4; ++d)
      vf[d] = *(const bf16x8*)
        &Vs[(d * 16 + l15) * 128 + (((w * 4 + quad) ^ l15) & 15) * 8];

    __syncthreads();                         // all waves done reading Ks/Vs

    if (it < 31) STAGEKV((it + 1) * 128);    // overwrite: overlaps full compute below

    f32x4 sacc[2][4] = {};
    __builtin_amdgcn_s_setprio(1);
#pragma unroll
    for (int kvt = 0; kvt < 2; ++kvt)
#pragma unroll
      for (int t = 0; t < 4; ++t)
#pragma unroll
        for (int kc = 0; kc < 2; ++kc)
          sacc[kvt][t] = __builtin_amdgcn_mfma_f32_16x16x32_bf16(
              kf[kvt][kc], qf[t][kc].v, sacc[kvt][t], 0, 0, 0);
    __builtin_amdgcn_s_setprio(0);

#pragma unroll
    for (int kvt = 0; kvt < 2; ++kvt)
#pragma unroll
      for (int t = 0; t < 4; ++t) {
        float p0 = __builtin_amdgcn_exp2f(sacc[kvt][t][0]);
        float p1 = __builtin_amdgcn_exp2f(sacc[kvt][t][1]);
        float p2 = __builtin_amdgcn_exp2f(sacc[kvt][t][2]);
        float p3 = __builtin_amdgcn_exp2f(sacc[kvt][t][3]);
        l_lane[t] += (p0 + p1) + (p2 + p3);
        uint2 pk; pk.x = pack2rn(p0, p1); pk.y = pack2rn(p2, p3);
        *(uint2*)&P32[((w * 4 + t) * 16 + l15) * 20 + kvt * 8 + quad * 2] = pk;
      }

    bf16x8 pf[4];
#pragma unroll
    for (int t = 0; t < 4; ++t)
      pf[t] = *(const bf16x8*)&P32[((w * 4 + t) * 16 + l15) * 20 + quad * 4];
    __builtin_amdgcn_s_setprio(1);
#pragma unroll
    for (int d = 0; d < 4; ++d)
#pragma unroll
      for (int t = 0; t < 4; ++t)
        Oacc[d][t] = __builtin_amdgcn_mfma_f32_16x16x32_bf16(vf[d], pf[t], Oacc[d][t],
                                                             0, 0, 0);
    __builtin_amdgcn_s_setprio(0);
  }
#undef STAGEKV

#pragma unroll
  for (int t = 0; t < 4; ++t) {
    l_lane[t] += __shfl_xor(l_lane[t], 16);
    l_lane[t] += __shfl_xor(l_lane[t], 32);
  }
  if (quad == 0) {
#pragma unroll
    for (int t = 0; t < 4; ++t) Lr[w][t][l15] = l_lane[t];
  }
  __syncthreads();
  float inv = 1.0f / (Lr[0][w][l15] + Lr[1][w][l15] + Lr[2][w][l15] + Lr[3][w][l15]);

  float* red = (float*)P32;
  u16* ob = attn_out + (size_t)(b * NQ_ + q0 + w * 16 + l15) * INNER_ + h * 64;
#pragma unroll
  for (int d = 0; d < 4; ++d) {
    __syncthreads();
#pragma unroll
    for (int t = 0; t < 4; ++t)
      *(f32x4*)&red[(w * 4 + t) * 256 + quad * 64 + l15 * 4] = Oacc[d][t];
    __syncthreads();
    f32x4 r = *(const f32x4*)&red[(0 * 4 + w) * 256 + quad * 64 + l15 * 4];
#pragma unroll
    for (int ww = 1; ww < 4; ++ww) {
      f32x4 c = *(const f32x4*)&red[(ww * 4 + w) * 256 + quad * 64 + l15 * 4];
      r[0] += c[0]; r[1] += c[1]; r[2] += c[2]; r[3] += c[3];
    }
    *(u32*)(ob + d * 16 + quad * 4)     = pack2(r[0] * inv, r[1] * inv);
    *(u32*)(ob + d * 16 + quad * 4 + 2) = pack2(r[2] * inv, r[3] * inv);
  }
}

// ---------------- driver ----------------
extern "C" void kernel_launch(void* const* d_in, const int* in_sizes, int n_in,
                              void* d_out, int out_size, void* d_ws, size_t ws_size,
                              hipStream_t stream) {
  const float* x    = (const float*)d_in[0];
  const float* ctx  = (const float*)d_in[1];
  const float* Wq   = (const float*)d_in[2];
  const float* Wkv  = (const float*)d_in[3];
  const float* Wout = (const float*)d_in[4];
  const float* bout = (const float*)d_in[5];

  char* ws = (char*)d_ws;
  u16* xb    = (u16*)(ws + (size_t)( 0u << 20));  // 4 MB  [dead after q_gemm]
  u16* ab    = (u16*)(ws + (size_t)( 0u << 20));  // 4 MB  [reuses xb]
  u16* ctxb  = (u16*)(ws + (size_t)( 4u << 20));  // 16 MB [dead after kv_gemm]
  u16* WqT   = (u16*)(ws + (size_t)(20u << 20));  // 2 MB
  u16* WkvT  = (u16*)(ws + (size_t)(22u << 20));  // 4 MB
  u16* WoutT = (u16*)(ws + (size_t)(26u << 20));  // 2 MB
  u16* qb    = (u16*)(ws + (size_t)(28u << 20));  // 4 MB
  u16* kb    = (u16*)(ws + (size_t)(32u << 20));  // 16 MB (K row-major bf16)
  u16* vTb   = (u16*)(ws + (size_t)(48u << 20));  // 16 MB (V transposed [bh*64+dh][NKV])

  // casts + weight transposes in one dispatch (fat cast blocks)
  prep<<<5376, 256, 0, stream>>>(x, ctx, Wq, Wkv, Wout, xb, ctxb, WqT, WkvT, WoutT);
  // q projection: 256 blocks, 64x128 tiles (full GPU)
  q_gemm<<<256, 256, 0, stream>>>(xb, WqT, qb);
  // kv projection: 256 blocks of 256x256, faithful 8-phase, 1 block/CU
  kv_gemm<<<256, 512, 0, stream>>>(ctxb, WkvT, kb, vTb);
  // fused softmax attention: 512 blocks x 256 threads, x=bh for XCD L2 locality
  attn_kernel<<<dim3(32, 16), 256, 0, stream>>>(qb, kb, vTb, ab);
  // out = attn Wout + b_out : fp32, 256 blocks
  out_gemm<<<256, 256, 0, stream>>>(ab, WoutT, (float*)d_out, bout);
}

// Round 9
// 213.474 us; speedup vs baseline: 1.1455x; 1.0377x over previous
//
#include <hip/hip_runtime.h>
#include <stdint.h>

// Problem constants
#define B_    2
#define NQ_   1024
#define NKV_  4096
#define DQ_   1024
#define H_    16
#define DH_   64
#define INNER_ 1024

typedef unsigned short u16;
typedef uint32_t u32;
typedef __bf16 bf16x8 __attribute__((ext_vector_type(8)));
typedef float  f32x4  __attribute__((ext_vector_type(4)));

__device__ __forceinline__ u16 f2bf(float x) {           // RNE
  union { float f; uint32_t u; } v; v.f = x;
  uint32_t r = v.u + 0x7FFFu + ((v.u >> 16) & 1u);
  return (u16)(r >> 16);
}
__device__ __forceinline__ u32 pack2(float a, float b) { // RNE pair
  return (u32)f2bf(a) | ((u32)f2bf(b) << 16);
}
__device__ __forceinline__ u32 pack2rn(float a, float b) { // fast RN via v_perm (3 VALU)
  union { float f; u32 u; } x, y; x.f = a; y.f = b;
  return __builtin_amdgcn_perm(y.u + 0x8000u, x.u + 0x8000u, 0x07060302u);
}
__device__ __forceinline__ float bf2f(u16 s) {
  union { float f; uint32_t u; } v; v.u = ((uint32_t)s) << 16; return v.f;
}

// async global->LDS, 16B/lane; lds base wave-uniform, hw adds lane*16
__device__ __forceinline__ void gload16(const void* g, void* l) {
  __builtin_amdgcn_global_load_lds((const __attribute__((address_space(1))) void*)g,
                                   (__attribute__((address_space(3))) void*)l,
                                   16, 0, 0);
}

// ---------------- fused prep: casts + weight transposes in ONE dispatch -----------------
// blocks [0,1280): fat casts (8 x float4 per thread); [1280,2304): Wq^T;
// [2304,4352): Wkv^T; [4352,5376): Wout^T.
__global__ __launch_bounds__(256) void prep(const float* __restrict__ x,
                                            const float* __restrict__ ctx,
                                            const float* __restrict__ Wq,
                                            const float* __restrict__ Wkv,
                                            const float* __restrict__ Wout,
                                            u16* __restrict__ xb,
                                            u16* __restrict__ ctxb,
                                            u16* __restrict__ WqT,
                                            u16* __restrict__ WkvT,
                                            u16* __restrict__ WoutT) {
  int bid = blockIdx.x;
  if (bid < 1280) {                        // elementwise cast, 32 elems/thread
    const float* src; u16* dst; int fbase;  // float4 units
    if (bid < 256) { src = x;   dst = xb;   fbase = bid * 2048; }
    else           { src = ctx; dst = ctxb; fbase = (bid - 256) * 2048; }
#pragma unroll
    for (int u = 0; u < 8; ++u) {
      int i = (fbase + u * 256 + threadIdx.x) * 4;
      float4 v = *(const float4*)(src + i);
      uint2 o; o.x = pack2(v.x, v.y); o.y = pack2(v.z, v.w);
      *(uint2*)(dst + i) = o;
    }
    return;
  }
  // transpose+cast W[K][N] -> Wt[N][K]
  __shared__ float tile[32][33];
  const float* W; u16* Wt; int K, N, local, nsh;
  int b2 = bid - 1280;
  if (b2 < 1024)      { W = Wq;   Wt = WqT;   K = 1024; N = 1024; local = b2;        nsh = 5; }
  else if (b2 < 3072) { W = Wkv;  Wt = WkvT;  K = 1024; N = 2048; local = b2 - 1024; nsh = 6; }
  else                { W = Wout; Wt = WoutT; K = 1024; N = 1024; local = b2 - 3072; nsh = 5; }
  int n0 = (local & ((1 << nsh) - 1)) * 32;
  int k0 = (local >> nsh) * 32;
  int tx = threadIdx.x & 31, ty = threadIdx.x >> 5;   // 32 x 8
  for (int i = ty; i < 32; i += 8)
    tile[i][tx] = W[(size_t)(k0 + i) * N + n0 + tx];
  __syncthreads();
  for (int i = ty; i < 32; i += 8)
    Wt[(size_t)(n0 + i) * K + k0 + tx] = f2bf(tile[tx][i]);
}

// ---------------- kv projection: 256x256 / BK=64 / FAITHFUL 8-phase schedule ------------
// R8-proven. 2 K-steps per iteration; counted vmcnt(6) only at ph4/ph8; stage ledger
// WAR-safe; every wait's targets >=4 phases old. Epilogues round-1 proven.
__global__ __launch_bounds__(512, 2) void kv_gemm(const u16* __restrict__ ctxb,
                                                  const u16* __restrict__ WkvT,
                                                  u16* __restrict__ kb,
                                                  u16* __restrict__ vTb) {
  __shared__ __align__(16) u16 As[2][256 * 64];   // 64 KiB
  __shared__ __align__(16) u16 Bs[2][256 * 64];   // 64 KiB
  const int tid = threadIdx.x;
  const int lane = tid & 63;
  const int w = tid >> 6;                 // 0..7
  const int wr = w >> 2, wc = w & 3;      // 2 x 4 waves -> wave panel 128M x 64N
  const int l15 = lane & 15, quad = lane >> 4;
  const int K = 1024;

  // XCD-chunked bijective swizzle
  int bid = blockIdx.x;
  int wgid = (bid & 7) * 32 + (bid >> 3);
  const int tm = wgid >> 3, tn = wgid & 7;
  const int m0 = tm * 256, n0 = tn * 256;
  const u16* Ag = ctxb + (size_t)m0 * K;
  const u16* Bg = WkvT + (size_t)n0 * K;

  // per-thread stage source offsets (u16 units): row-reorder + chunk XOR pre-swizzle
  size_t offA[2][2], offB[2][2];
#pragma unroll
  for (int ah = 0; ah < 2; ++ah)
#pragma unroll
    for (int p = 0; p < 2; ++p) {
      int c = p * 512 + (w << 6) + lane;  // chunk id within 16 KiB region
      int s = ah * 128 + (c >> 3);        // LDS slot (reordered row)
      int col = ((c & 7) ^ (s & 7)) << 3; // pre-swizzled source column (bf16)
      int rA = ((s >> 6) & 1) * 128 + ((s >> 7) & 1) * 64 + (s & 63);
      int rB = ((s >> 5) & 3) * 64 + ((s >> 7) & 1) * 32 + (s & 31);
      offA[ah][p] = (size_t)rA * 1024 + col;
      offB[ah][p] = (size_t)rB * 1024 + col;
    }

#define STAGE_A(bufi, ah, kk) do { \
    gload16(Ag + offA[ah][0] + (kk), &As[bufi][(ah) * 8192 + (w << 9)]); \
    gload16(Ag + offA[ah][1] + (kk), &As[bufi][(ah) * 8192 + 4096 + (w << 9)]); \
  } while (0)
#define STAGE_B(bufi, bh, kk) do { \
    gload16(Bg + offB[bh][0] + (kk), &Bs[bufi][(bh) * 8192 + (w << 9)]); \
    gload16(Bg + offB[bh][1] + (kk), &Bs[bufi][(bh) * 8192 + 4096 + (w << 9)]); \
  } while (0)
#define LDA2(dst, i8, bufi) do { \
    const int _s = ((i8) >> 2) * 128 + wr * 64 + ((i8) & 3) * 16 + l15; \
    const u16* _p = &As[bufi][_s * 64]; const int _x = _s & 7; \
    dst[0] = *(const bf16x8*)&_p[(quad ^ _x) << 3]; \
    dst[1] = *(const bf16x8*)&_p[((quad + 4) ^ _x) << 3]; \
  } while (0)
#define LDB2(dst, j, bufi) do { \
    const int _s = ((j) >> 1) * 128 + wc * 32 + ((j) & 1) * 16 + l15; \
    const u16* _p = &Bs[bufi][_s * 64]; const int _x = _s & 7; \
    dst[0] = *(const bf16x8*)&_p[(quad ^ _x) << 3]; \
    dst[1] = *(const bf16x8*)&_p[((quad + 4) ^ _x) << 3]; \
  } while (0)
#define MF(i0, j0, bb) do { \
    _Pragma("unroll") \
    for (int _i = 0; _i < 4; ++_i) { \
      acc[(i0) + _i][(j0)    ] = __builtin_amdgcn_mfma_f32_16x16x32_bf16(a[_i][0], bb[0][0], acc[(i0) + _i][(j0)    ], 0, 0, 0); \
      acc[(i0) + _i][(j0)    ] = __builtin_amdgcn_mfma_f32_16x16x32_bf16(a[_i][1], bb[0][1], acc[(i0) + _i][(j0)    ], 0, 0, 0); \
      acc[(i0) + _i][(j0) + 1] = __builtin_amdgcn_mfma_f32_16x16x32_bf16(a[_i][0], bb[1][0], acc[(i0) + _i][(j0) + 1], 0, 0, 0); \
      acc[(i0) + _i][(j0) + 1] = __builtin_amdgcn_mfma_f32_16x16x32_bf16(a[_i][1], bb[1][1], acc[(i0) + _i][(j0) + 1], 0, 0, 0); \
    } \
  } while (0)
#define BAR()   __builtin_amdgcn_s_barrier()
#define LGKM0() asm volatile("s_waitcnt lgkmcnt(0)" ::: "memory")

  f32x4 acc[8][4] = {};
  bf16x8 a[4][2], b[2][2], c2[2][2];

  // prologue: step0 full (Aa,Ba,Bb,Ab) + step1 trio (Aa,Ba,Bb) = 14 loads
  STAGE_A(0, 0, 0);
  STAGE_B(0, 0, 0);
  STAGE_B(0, 1, 0);
  STAGE_A(0, 1, 0);
  STAGE_A(1, 0, 64);
  STAGE_B(1, 0, 64);
  STAGE_B(1, 1, 64);
  asm volatile("s_waitcnt vmcnt(6)" ::: "memory");   // step0's 8 loads complete
  BAR();

#define HALF(bufi, kAb, kNext, STG, WMID, WEND) do { \
    LDB2(b[0], 0, bufi); LDB2(b[1], 1, bufi); \
    LDA2(a[0], 0, bufi); LDA2(a[1], 1, bufi); LDA2(a[2], 2, bufi); LDA2(a[3], 3, bufi); \
    if (kAb >= 0) STAGE_A((bufi) ^ 1, 1, kAb); \
    BAR(); LGKM0(); \
    __builtin_amdgcn_s_setprio(1); MF(0, 0, b); __builtin_amdgcn_s_setprio(0); \
    BAR(); \
    LDB2(c2[0], 2, bufi); LDB2(c2[1], 3, bufi); \
    if (STG) STAGE_A(bufi, 0, kNext); \
    BAR(); LGKM0(); \
    __builtin_amdgcn_s_setprio(1); MF(0, 2, c2); __builtin_amdgcn_s_setprio(0); \
    BAR(); \
    LDA2(a[0], 4, bufi); LDA2(a[1], 5, bufi); LDA2(a[2], 6, bufi); LDA2(a[3], 7, bufi); \
    if (STG) STAGE_B(bufi, 0, kNext); \
    BAR(); LGKM0(); \
    __builtin_amdgcn_s_setprio(1); MF(4, 0, b); __builtin_amdgcn_s_setprio(0); \
    BAR(); \
    if (STG) STAGE_B(bufi, 1, kNext); \
    BAR(); \
    __builtin_amdgcn_s_setprio(1); MF(4, 2, c2); __builtin_amdgcn_s_setprio(0); \
    WMID; \
    BAR(); \
  } while (0)

  for (int i = 0; i < 7; ++i) {
    const int k2 = i * 128;
    HALF(0, k2 + 64, k2 + 128, 1,
         asm volatile("s_waitcnt vmcnt(6)" ::: "memory"), );
    HALF(1, k2 + 128, k2 + 192, 1,
         asm volatile("s_waitcnt vmcnt(6)" ::: "memory"), );
  }
  HALF(0, 960, 0, 0,
       asm volatile("s_waitcnt vmcnt(0)" ::: "memory"), );
  HALF(1, -1, 0, 0, , );

#undef HALF
#undef BAR
#undef LGKM0

  // epilogue (round-1 proven): tn<4 -> K row-major, tn>=4 -> V transposed scatter
  if (tn < 4) {
#pragma unroll
    for (int i8 = 0; i8 < 8; ++i8)
#pragma unroll
      for (int j = 0; j < 4; ++j) {
        int col = n0 + wc * 64 + j * 16 + l15;
#pragma unroll
        for (int r = 0; r < 4; ++r) {
          int row = m0 + wr * 128 + i8 * 16 + quad * 4 + r;
          kb[(size_t)row * 1024 + col] = f2bf(acc[i8][j][r]);
        }
      }
  } else {
    const int bb_ = m0 >> 12;
#pragma unroll
    for (int i8 = 0; i8 < 8; ++i8) {
      int kvr = (m0 & 4095) + wr * 128 + i8 * 16 + quad * 4;
#pragma unroll
      for (int j = 0; j < 4; ++j) {
        int c = (n0 - 1024) + wc * 64 + j * 16 + l15;
        int h = c >> 6, dh = c & 63;
        uint2 st;
        st.x = pack2(acc[i8][j][0], acc[i8][j][1]);
        st.y = pack2(acc[i8][j][2], acc[i8][j][3]);
        *(uint2*)&vTb[((size_t)((bb_ * 16 + h) * 64 + dh)) * NKV_ + kvr] = st;
      }
    }
  }
#undef STAGE_A
#undef STAGE_B
#undef LDA2
#undef LDB2
#undef MF
}

// ---------------- out-proj GEMM: 64x128 tiles -> 256 blocks (full GPU) ------------------
__global__ __launch_bounds__(256) void out_gemm(const u16* __restrict__ A,
                                                const u16* __restrict__ Bt,
                                                float* __restrict__ Cout,
                                                const float* __restrict__ bias) {
  __shared__ __align__(16) u16 As[64 * 32];    // 4 KB
  __shared__ __align__(16) u16 Bs[128 * 32];   // 8 KB
  const int tid = threadIdx.x;
  const int lane = tid & 63;
  const int w = tid >> 6;
  const int wr = w >> 1, wc = w & 1;           // wave covers 32M x 64N
  const int l15 = lane & 15, quad = lane >> 4;
  const int unit = blockIdx.x;
  const int m0 = (unit >> 3) * 64, n0 = (unit & 7) * 128;
  const int K = 1024, N = 1024;

  const u16* Ab = A + (size_t)m0 * K;
  const u16* Bb = Bt + (size_t)n0 * K;
  f32x4 acc[2][4] = {};

  const int ar = tid >> 2, ac = (tid & 3) << 3;          // A: 256 chunks, 1/thread
  const int q1 = w * 64 + lane, q2 = q1 + 256;           // B: 512 chunks, 2/thread
  const int br1 = q1 >> 2, bc1 = (q1 & 3) << 3;
  const int br2 = q2 >> 2, bc2 = (q2 & 3) << 3;

  for (int k0 = 0; k0 < K; k0 += 32) {
    __syncthreads();
    gload16(Ab + (size_t)ar * K + k0 + ac, &As[w * 512]);
    gload16(Bb + (size_t)br1 * K + k0 + bc1, &Bs[w * 512]);
    gload16(Bb + (size_t)br2 * K + k0 + bc2, &Bs[2048 + w * 512]);
    __syncthreads();
    bf16x8 af[2], bfr[4];
#pragma unroll
    for (int i = 0; i < 2; ++i)
      af[i] = *(const bf16x8*)&As[(wr * 32 + i * 16 + l15) * 32 + quad * 8];
#pragma unroll
    for (int j = 0; j < 4; ++j)
      bfr[j] = *(const bf16x8*)&Bs[(wc * 64 + j * 16 + l15) * 32 + quad * 8];
#pragma unroll
    for (int i = 0; i < 2; ++i)
#pragma unroll
      for (int j = 0; j < 4; ++j)
        acc[i][j] = __builtin_amdgcn_mfma_f32_16x16x32_bf16(af[i], bfr[j], acc[i][j], 0, 0, 0);
  }

#pragma unroll
  for (int i = 0; i < 2; ++i)
#pragma unroll
    for (int j = 0; j < 4; ++j) {
      int col = n0 + wc * 64 + j * 16 + l15;
      float bv = bias[col];
#pragma unroll
      for (int r = 0; r < 4; ++r) {
        int row = m0 + wr * 32 + i * 16 + quad * 4 + r;
        Cout[(size_t)row * N + col] = acc[i][j][r] + bv;
      }
    }
}

// ---------------- flash attention + FUSED Q-PROJECTION prologue -------------------------
// Each block computes its own private 64x64 Q-slice (rows q0..q0+64, cols h*64..h*64+64)
// in a 16-step BK=64 mini-GEMM (xb/WqT tiles staged into Ks with the proven XOR swizzle;
// conflict-free fragment reads), bounces the f32 accumulator through Vs (64x64 f32,
// col^((row&7)*8) swizzle -> 2-way free reads), and builds qf fragments bit-compatible
// with the old qb path. This deletes the q_gemm dispatch + qb round-trip entirely.
// Main loop = R4-exact proven structure.
__global__ __launch_bounds__(256, 2) void attn_kernel(const u16* __restrict__ xb,
                                                      const u16* __restrict__ WqT,
                                                      const u16* __restrict__ kb,
                                                      const u16* __restrict__ vT,
                                                      u16* __restrict__ attn_out) {
  __shared__ __align__(16) u16 Ks[128 * 64];       // [kv][dh], 16B groups XOR-swizzled
  __shared__ __align__(16) u16 Vs[64 * 128];       // [dh][kv], XOR-swizzled (16 groups/row)
  __shared__ __align__(16) u32 P32[4 * 4 * 16 * 20]; // [w][t][q=l15][20]: wave-private pairs
  __shared__ float Lr[4][4][16];                   // [w][t][q] partial l

  const int tid = threadIdx.x;
  const int lane = tid & 63;
  const int w = tid >> 6;
  const int l15 = lane & 15, quad = lane >> 4;
  const int bh = blockIdx.x, b = bh >> 4, h = bh & 15;
  const int q0 = blockIdx.y * 64;

  const float SC = 0.125f * 1.44269504088896340736f;   // dh^-0.5 * log2(e)
  union { u16 s[8]; bf16x8 v; } qf[4][2];

  // ---- Q-projection prologue ----
  {
    const u16* Axb = xb + (size_t)(b * NQ_ + q0) * 1024;     // 64 rows of x (bf16)
    const u16* Bwq = WqT + (size_t)(h * 64) * 1024;          // 64 Wq-columns (rows of WqT)
    // 64x64 tile = 512 chunks of 16B; chunk c: row=c>>3, g=c&7; src pre-swizzled g^row&7
    const int c1 = tid, c2 = tid + 256;
    const int r1 = c1 >> 3, g1 = c1 & 7;
    const int r2 = c2 >> 3, g2 = c2 & 7;
    const size_t sO1 = (size_t)r1 * 1024 + (size_t)((g1 ^ (r1 & 7)) << 3);
    const size_t sO2 = (size_t)r2 * 1024 + (size_t)((g2 ^ (r2 & 7)) << 3);
    f32x4 qacc[4] = {};
    const int x7 = l15 & 7;
    for (int k0 = 0; k0 < 1024; k0 += 64) {
      __syncthreads();
      gload16(Axb + sO1 + k0, &Ks[w * 512]);            // A chunks [0,256)
      gload16(Axb + sO2 + k0, &Ks[2048 + w * 512]);     // A chunks [256,512)
      gload16(Bwq + sO1 + k0, &Ks[4096 + w * 512]);     // B chunks [0,256)
      gload16(Bwq + sO2 + k0, &Ks[6144 + w * 512]);     // B chunks [256,512)
      __syncthreads();
      bf16x8 af[2], bfr[4][2];
#pragma unroll
      for (int kc = 0; kc < 2; ++kc) {
        af[kc] = *(const bf16x8*)&Ks[(w * 16 + l15) * 64 + (((kc * 4 + quad) ^ x7) << 3)];
#pragma unroll
        for (int j = 0; j < 4; ++j)
          bfr[j][kc] = *(const bf16x8*)
            &Ks[4096 + (j * 16 + l15) * 64 + (((kc * 4 + quad) ^ x7) << 3)];
      }
#pragma unroll
      for (int j = 0; j < 4; ++j) {
        qacc[j] = __builtin_amdgcn_mfma_f32_16x16x32_bf16(af[0], bfr[j][0], qacc[j], 0, 0, 0);
        qacc[j] = __builtin_amdgcn_mfma_f32_16x16x32_bf16(af[1], bfr[j][1], qacc[j], 0, 0, 0);
      }
    }
    // bounce: Vs as 64x64 f32, col' = col ^ ((row&7)*8)
    float* Q64 = (float*)Vs;
#pragma unroll
    for (int j = 0; j < 4; ++j)
#pragma unroll
      for (int r = 0; r < 4; ++r) {
        int row = w * 16 + quad * 4 + r;
        Q64[row * 64 + ((j * 16 + l15) ^ ((row & 7) * 8))] = qacc[j][r];
      }
    __syncthreads();
#pragma unroll
    for (int t = 0; t < 4; ++t)
#pragma unroll
      for (int kc = 0; kc < 2; ++kc) {
        const float* qp = Q64 + (t * 16 + l15) * 64 + (((kc * 4 + quad) ^ x7) * 8);
        f32x4 lo = *(const f32x4*)qp;
        f32x4 hi = *(const f32x4*)(qp + 4);
#pragma unroll
        for (int e = 0; e < 4; ++e) {
          qf[t][kc].s[e]     = f2bf(lo[e] * SC);
          qf[t][kc].s[e + 4] = f2bf(hi[e] * SC);
        }
      }
    __syncthreads();   // all waves done reading Vs before STAGEKV overwrites it
  }

#define STAGEKV(j0) do { \
    _Pragma("unroll") \
    for (int i_ = 0; i_ < 4; ++i_) { \
      int s_ = i_ * 256 + tid; \
      int kr = s_ >> 3, kg = (s_ ^ kr) & 7; \
      gload16(kb + (size_t)(b * NKV_ + (j0) + kr) * 1024 + h * 64 + kg * 8, \
              &Ks[(i_ * 256 + w * 64) * 8]); \
      int vr = s_ >> 4, vg = (s_ ^ vr) & 15; \
      gload16(vT + (size_t)(bh * 64 + vr) * NKV_ + (j0) + vg * 8, \
              &Vs[(i_ * 256 + w * 64) * 8]); \
    } \
  } while (0)

  f32x4 Oacc[4][4] = {};
  float l_lane[4] = {0.f, 0.f, 0.f, 0.f};

  STAGEKV(0);                                // prologue: tile 0

  for (int it = 0; it < 32; ++it) {
    __syncthreads();                         // tile `it` staged (vmcnt drained per-wave)

    // fragment reads for tile `it` (this wave's complete K/V consumption)
    bf16x8 kf[2][2];
#pragma unroll
    for (int kvt = 0; kvt < 2; ++kvt)
#pragma unroll
      for (int kc = 0; kc < 2; ++kc)
        kf[kvt][kc] = *(const bf16x8*)
          &Ks[(w * 32 + kvt * 16 + l15) * 64 + (((kc * 4 + quad) ^ l15) & 7) * 8];
    bf16x8 vf[4];
#pragma unroll
    for (int d = 0; d < 4; ++d)
      vf[d] = *(const bf16x8*)
        &Vs[(d * 16 + l15) * 128 + (((w * 4 + quad) ^ l15) & 15) * 8];

    __syncthreads();                         // all waves done reading Ks/Vs

    if (it < 31) STAGEKV((it + 1) * 128);    // overwrite: overlaps full compute below

    f32x4 sacc[2][4] = {};
    __builtin_amdgcn_s_setprio(1);
#pragma unroll
    for (int kvt = 0; kvt < 2; ++kvt)
#pragma unroll
      for (int t = 0; t < 4; ++t)
#pragma unroll
        for (int kc = 0; kc < 2; ++kc)
          sacc[kvt][t] = __builtin_amdgcn_mfma_f32_16x16x32_bf16(
              kf[kvt][kc], qf[t][kc].v, sacc[kvt][t], 0, 0, 0);
    __builtin_amdgcn_s_setprio(0);

#pragma unroll
    for (int kvt = 0; kvt < 2; ++kvt)
#pragma unroll
      for (int t = 0; t < 4; ++t) {
        float p0 = __builtin_amdgcn_exp2f(sacc[kvt][t][0]);
        float p1 = __builtin_amdgcn_exp2f(sacc[kvt][t][1]);
        float p2 = __builtin_amdgcn_exp2f(sacc[kvt][t][2]);
        float p3 = __builtin_amdgcn_exp2f(sacc[kvt][t][3]);
        l_lane[t] += (p0 + p1) + (p2 + p3);
        uint2 pk; pk.x = pack2rn(p0, p1); pk.y = pack2rn(p2, p3);
        *(uint2*)&P32[((w * 4 + t) * 16 + l15) * 20 + kvt * 8 + quad * 2] = pk;
      }

    bf16x8 pf[4];
#pragma unroll
    for (int t = 0; t < 4; ++t)
      pf[t] = *(const bf16x8*)&P32[((w * 4 + t) * 16 + l15) * 20 + quad * 4];
    __builtin_amdgcn_s_setprio(1);
#pragma unroll
    for (int d = 0; d < 4; ++d)
#pragma unroll
      for (int t = 0; t < 4; ++t)
        Oacc[d][t] = __builtin_amdgcn_mfma_f32_16x16x32_bf16(vf[d], pf[t], Oacc[d][t],
                                                             0, 0, 0);
    __builtin_amdgcn_s_setprio(0);
  }
#undef STAGEKV

#pragma unroll
  for (int t = 0; t < 4; ++t) {
    l_lane[t] += __shfl_xor(l_lane[t], 16);
    l_lane[t] += __shfl_xor(l_lane[t], 32);
  }
  if (quad == 0) {
#pragma unroll
    for (int t = 0; t < 4; ++t) Lr[w][t][l15] = l_lane[t];
  }
  __syncthreads();
  float inv = 1.0f / (Lr[0][w][l15] + Lr[1][w][l15] + Lr[2][w][l15] + Lr[3][w][l15]);

  float* red = (float*)P32;
  u16* ob = attn_out + (size_t)(b * NQ_ + q0 + w * 16 + l15) * INNER_ + h * 64;
#pragma unroll
  for (int d = 0; d < 4; ++d) {
    __syncthreads();
#pragma unroll
    for (int t = 0; t < 4; ++t)
      *(f32x4*)&red[(w * 4 + t) * 256 + quad * 64 + l15 * 4] = Oacc[d][t];
    __syncthreads();
    f32x4 r = *(const f32x4*)&red[(0 * 4 + w) * 256 + quad * 64 + l15 * 4];
#pragma unroll
    for (int ww = 1; ww < 4; ++ww) {
      f32x4 c = *(const f32x4*)&red[(ww * 4 + w) * 256 + quad * 64 + l15 * 4];
      r[0] += c[0]; r[1] += c[1]; r[2] += c[2]; r[3] += c[3];
    }
    *(u32*)(ob + d * 16 + quad * 4)     = pack2(r[0] * inv, r[1] * inv);
    *(u32*)(ob + d * 16 + quad * 4 + 2) = pack2(r[2] * inv, r[3] * inv);
  }
}

// ---------------- driver ----------------
extern "C" void kernel_launch(void* const* d_in, const int* in_sizes, int n_in,
                              void* d_out, int out_size, void* d_ws, size_t ws_size,
                              hipStream_t stream) {
  const float* x    = (const float*)d_in[0];
  const float* ctx  = (const float*)d_in[1];
  const float* Wq   = (const float*)d_in[2];
  const float* Wkv  = (const float*)d_in[3];
  const float* Wout = (const float*)d_in[4];
  const float* bout = (const float*)d_in[5];

  char* ws = (char*)d_ws;
  u16* xb    = (u16*)(ws + (size_t)( 0u << 20));  // 4 MB  [live through attn prologue]
  u16* ctxb  = (u16*)(ws + (size_t)( 4u << 20));  // 16 MB [dead after kv_gemm]
  u16* WqT   = (u16*)(ws + (size_t)(20u << 20));  // 2 MB  [live through attn prologue]
  u16* WkvT  = (u16*)(ws + (size_t)(22u << 20));  // 4 MB
  u16* WoutT = (u16*)(ws + (size_t)(26u << 20));  // 2 MB
  u16* ab    = (u16*)(ws + (size_t)(28u << 20));  // 4 MB  [old qb slot; NOT aliasing xb]
  u16* kb    = (u16*)(ws + (size_t)(32u << 20));  // 16 MB (K row-major bf16)
  u16* vTb   = (u16*)(ws + (size_t)(48u << 20));  // 16 MB (V transposed [bh*64+dh][NKV])

  // casts + weight transposes in one dispatch (fat cast blocks)
  prep<<<5376, 256, 0, stream>>>(x, ctx, Wq, Wkv, Wout, xb, ctxb, WqT, WkvT, WoutT);
  // kv projection: 256 blocks of 256x256, faithful 8-phase, 1 block/CU
  kv_gemm<<<256, 512, 0, stream>>>(ctxb, WkvT, kb, vTb);
  // fused q-projection + softmax attention: 512 blocks x 256 threads
  attn_kernel<<<dim3(32, 16), 256, 0, stream>>>(xb, WqT, kb, vTb, ab);
  // out = attn Wout + b_out : fp32, 256 blocks
  out_gemm<<<256, 256, 0, stream>>>(ab, WoutT, (float*)d_out, bout);
}

// Round 10
// 208.776 us; speedup vs baseline: 1.1713x; 1.0225x over previous
//
#include <hip/hip_runtime.h>
#include <stdint.h>

// Problem constants
#define B_    2
#define NQ_   1024
#define NKV_  4096
#define DQ_   1024
#define H_    16
#define DH_   64
#define INNER_ 1024

typedef unsigned short u16;
typedef uint32_t u32;
typedef __bf16 bf16x8 __attribute__((ext_vector_type(8)));
typedef float  f32x4  __attribute__((ext_vector_type(4)));

__device__ __forceinline__ u16 f2bf(float x) {           // RNE
  union { float f; uint32_t u; } v; v.f = x;
  uint32_t r = v.u + 0x7FFFu + ((v.u >> 16) & 1u);
  return (u16)(r >> 16);
}
__device__ __forceinline__ u32 pack2(float a, float b) { // RNE pair
  return (u32)f2bf(a) | ((u32)f2bf(b) << 16);
}
__device__ __forceinline__ u32 pack2rn(float a, float b) { // fast RN via v_perm (3 VALU)
  union { float f; u32 u; } x, y; x.f = a; y.f = b;
  return __builtin_amdgcn_perm(y.u + 0x8000u, x.u + 0x8000u, 0x07060302u);
}
__device__ __forceinline__ float bf2f(u16 s) {
  union { float f; uint32_t u; } v; v.u = ((uint32_t)s) << 16; return v.f;
}

// async global->LDS, 16B/lane; lds base wave-uniform, hw adds lane*16
__device__ __forceinline__ void gload16(const void* g, void* l) {
  __builtin_amdgcn_global_load_lds((const __attribute__((address_space(1))) void*)g,
                                   (__attribute__((address_space(3))) void*)l,
                                   16, 0, 0);
}

// ---------------- fused prep: casts + weight transposes in ONE dispatch -----------------
// blocks [0,1280): fat casts (8 x float4 per thread); [1280,2304): Wq^T;
// [2304,4352): Wkv^T; [4352,5376): Wout^T.
__global__ __launch_bounds__(256) void prep(const float* __restrict__ x,
                                            const float* __restrict__ ctx,
                                            const float* __restrict__ Wq,
                                            const float* __restrict__ Wkv,
                                            const float* __restrict__ Wout,
                                            u16* __restrict__ xb,
                                            u16* __restrict__ ctxb,
                                            u16* __restrict__ WqT,
                                            u16* __restrict__ WkvT,
                                            u16* __restrict__ WoutT) {
  int bid = blockIdx.x;
  if (bid < 1280) {                        // elementwise cast, 32 elems/thread
    const float* src; u16* dst; int fbase;  // float4 units
    if (bid < 256) { src = x;   dst = xb;   fbase = bid * 2048; }
    else           { src = ctx; dst = ctxb; fbase = (bid - 256) * 2048; }
#pragma unroll
    for (int u = 0; u < 8; ++u) {
      int i = (fbase + u * 256 + threadIdx.x) * 4;
      float4 v = *(const float4*)(src + i);
      uint2 o; o.x = pack2(v.x, v.y); o.y = pack2(v.z, v.w);
      *(uint2*)(dst + i) = o;
    }
    return;
  }
  // transpose+cast W[K][N] -> Wt[N][K]
  __shared__ float tile[32][33];
  const float* W; u16* Wt; int K, N, local, nsh;
  int b2 = bid - 1280;
  if (b2 < 1024)      { W = Wq;   Wt = WqT;   K = 1024; N = 1024; local = b2;        nsh = 5; }
  else if (b2 < 3072) { W = Wkv;  Wt = WkvT;  K = 1024; N = 2048; local = b2 - 1024; nsh = 6; }
  else                { W = Wout; Wt = WoutT; K = 1024; N = 1024; local = b2 - 3072; nsh = 5; }
  int n0 = (local & ((1 << nsh) - 1)) * 32;
  int k0 = (local >> nsh) * 32;
  int tx = threadIdx.x & 31, ty = threadIdx.x >> 5;   // 32 x 8
  for (int i = ty; i < 32; i += 8)
    tile[i][tx] = W[(size_t)(k0 + i) * N + n0 + tx];
  __syncthreads();
  // packed u32 stores (2 k-consecutive bf16 per store; 2-way tile reads = free)
  int tx2 = threadIdx.x & 15, ty2 = threadIdx.x >> 4;  // 16 x 16
  for (int i = ty2; i < 32; i += 16)
    *(u32*)&Wt[(size_t)(n0 + i) * K + k0 + tx2 * 2] =
        pack2(tile[tx2 * 2][i], tile[tx2 * 2 + 1][i]);
}

// ---------------- kv projection: 256x256 / BK=64 / FAITHFUL 8-phase schedule ------------
// R8-proven. 2 K-steps per iteration; counted vmcnt(6) only at ph4/ph8; stage ledger
// WAR-safe; every wait's targets >=4 phases old. Epilogues round-1 proven.
__global__ __launch_bounds__(512, 2) void kv_gemm(const u16* __restrict__ ctxb,
                                                  const u16* __restrict__ WkvT,
                                                  u16* __restrict__ kb,
                                                  u16* __restrict__ vTb) {
  __shared__ __align__(16) u16 As[2][256 * 64];   // 64 KiB
  __shared__ __align__(16) u16 Bs[2][256 * 64];   // 64 KiB
  const int tid = threadIdx.x;
  const int lane = tid & 63;
  const int w = tid >> 6;                 // 0..7
  const int wr = w >> 2, wc = w & 3;      // 2 x 4 waves -> wave panel 128M x 64N
  const int l15 = lane & 15, quad = lane >> 4;
  const int K = 1024;

  // XCD-chunked bijective swizzle
  int bid = blockIdx.x;
  int wgid = (bid & 7) * 32 + (bid >> 3);
  const int tm = wgid >> 3, tn = wgid & 7;
  const int m0 = tm * 256, n0 = tn * 256;
  const u16* Ag = ctxb + (size_t)m0 * K;
  const u16* Bg = WkvT + (size_t)n0 * K;

  // per-thread stage source offsets (u16 units): row-reorder + chunk XOR pre-swizzle
  size_t offA[2][2], offB[2][2];
#pragma unroll
  for (int ah = 0; ah < 2; ++ah)
#pragma unroll
    for (int p = 0; p < 2; ++p) {
      int c = p * 512 + (w << 6) + lane;  // chunk id within 16 KiB region
      int s = ah * 128 + (c >> 3);        // LDS slot (reordered row)
      int col = ((c & 7) ^ (s & 7)) << 3; // pre-swizzled source column (bf16)
      int rA = ((s >> 6) & 1) * 128 + ((s >> 7) & 1) * 64 + (s & 63);
      int rB = ((s >> 5) & 3) * 64 + ((s >> 7) & 1) * 32 + (s & 31);
      offA[ah][p] = (size_t)rA * 1024 + col;
      offB[ah][p] = (size_t)rB * 1024 + col;
    }

#define STAGE_A(bufi, ah, kk) do { \
    gload16(Ag + offA[ah][0] + (kk), &As[bufi][(ah) * 8192 + (w << 9)]); \
    gload16(Ag + offA[ah][1] + (kk), &As[bufi][(ah) * 8192 + 4096 + (w << 9)]); \
  } while (0)
#define STAGE_B(bufi, bh, kk) do { \
    gload16(Bg + offB[bh][0] + (kk), &Bs[bufi][(bh) * 8192 + (w << 9)]); \
    gload16(Bg + offB[bh][1] + (kk), &Bs[bufi][(bh) * 8192 + 4096 + (w << 9)]); \
  } while (0)
#define LDA2(dst, i8, bufi) do { \
    const int _s = ((i8) >> 2) * 128 + wr * 64 + ((i8) & 3) * 16 + l15; \
    const u16* _p = &As[bufi][_s * 64]; const int _x = _s & 7; \
    dst[0] = *(const bf16x8*)&_p[(quad ^ _x) << 3]; \
    dst[1] = *(const bf16x8*)&_p[((quad + 4) ^ _x) << 3]; \
  } while (0)
#define LDB2(dst, j, bufi) do { \
    const int _s = ((j) >> 1) * 128 + wc * 32 + ((j) & 1) * 16 + l15; \
    const u16* _p = &Bs[bufi][_s * 64]; const int _x = _s & 7; \
    dst[0] = *(const bf16x8*)&_p[(quad ^ _x) << 3]; \
    dst[1] = *(const bf16x8*)&_p[((quad + 4) ^ _x) << 3]; \
  } while (0)
#define MF(i0, j0, bb) do { \
    _Pragma("unroll") \
    for (int _i = 0; _i < 4; ++_i) { \
      acc[(i0) + _i][(j0)    ] = __builtin_amdgcn_mfma_f32_16x16x32_bf16(a[_i][0], bb[0][0], acc[(i0) + _i][(j0)    ], 0, 0, 0); \
      acc[(i0) + _i][(j0)    ] = __builtin_amdgcn_mfma_f32_16x16x32_bf16(a[_i][1], bb[0][1], acc[(i0) + _i][(j0)    ], 0, 0, 0); \
      acc[(i0) + _i][(j0) + 1] = __builtin_amdgcn_mfma_f32_16x16x32_bf16(a[_i][0], bb[1][0], acc[(i0) + _i][(j0) + 1], 0, 0, 0); \
      acc[(i0) + _i][(j0) + 1] = __builtin_amdgcn_mfma_f32_16x16x32_bf16(a[_i][1], bb[1][1], acc[(i0) + _i][(j0) + 1], 0, 0, 0); \
    } \
  } while (0)
#define BAR()   __builtin_amdgcn_s_barrier()
#define LGKM0() asm volatile("s_waitcnt lgkmcnt(0)" ::: "memory")

  f32x4 acc[8][4] = {};
  bf16x8 a[4][2], b[2][2], c2[2][2];

  // prologue: step0 full (Aa,Ba,Bb,Ab) + step1 trio (Aa,Ba,Bb) = 14 loads
  STAGE_A(0, 0, 0);
  STAGE_B(0, 0, 0);
  STAGE_B(0, 1, 0);
  STAGE_A(0, 1, 0);
  STAGE_A(1, 0, 64);
  STAGE_B(1, 0, 64);
  STAGE_B(1, 1, 64);
  asm volatile("s_waitcnt vmcnt(6)" ::: "memory");   // step0's 8 loads complete
  BAR();

#define HALF(bufi, kAb, kNext, STG, WMID, WEND) do { \
    LDB2(b[0], 0, bufi); LDB2(b[1], 1, bufi); \
    LDA2(a[0], 0, bufi); LDA2(a[1], 1, bufi); LDA2(a[2], 2, bufi); LDA2(a[3], 3, bufi); \
    if (kAb >= 0) STAGE_A((bufi) ^ 1, 1, kAb); \
    BAR(); LGKM0(); \
    __builtin_amdgcn_s_setprio(1); MF(0, 0, b); __builtin_amdgcn_s_setprio(0); \
    BAR(); \
    LDB2(c2[0], 2, bufi); LDB2(c2[1], 3, bufi); \
    if (STG) STAGE_A(bufi, 0, kNext); \
    BAR(); LGKM0(); \
    __builtin_amdgcn_s_setprio(1); MF(0, 2, c2); __builtin_amdgcn_s_setprio(0); \
    BAR(); \
    LDA2(a[0], 4, bufi); LDA2(a[1], 5, bufi); LDA2(a[2], 6, bufi); LDA2(a[3], 7, bufi); \
    if (STG) STAGE_B(bufi, 0, kNext); \
    BAR(); LGKM0(); \
    __builtin_amdgcn_s_setprio(1); MF(4, 0, b); __builtin_amdgcn_s_setprio(0); \
    BAR(); \
    if (STG) STAGE_B(bufi, 1, kNext); \
    BAR(); \
    __builtin_amdgcn_s_setprio(1); MF(4, 2, c2); __builtin_amdgcn_s_setprio(0); \
    WMID; \
    BAR(); \
  } while (0)

  for (int i = 0; i < 7; ++i) {
    const int k2 = i * 128;
    HALF(0, k2 + 64, k2 + 128, 1,
         asm volatile("s_waitcnt vmcnt(6)" ::: "memory"), );
    HALF(1, k2 + 128, k2 + 192, 1,
         asm volatile("s_waitcnt vmcnt(6)" ::: "memory"), );
  }
  HALF(0, 960, 0, 0,
       asm volatile("s_waitcnt vmcnt(0)" ::: "memory"), );
  HALF(1, -1, 0, 0, , );

#undef HALF
#undef BAR
#undef LGKM0

  // epilogue (round-1 proven): tn<4 -> K row-major, tn>=4 -> V transposed scatter
  if (tn < 4) {
#pragma unroll
    for (int i8 = 0; i8 < 8; ++i8)
#pragma unroll
      for (int j = 0; j < 4; ++j) {
        int col = n0 + wc * 64 + j * 16 + l15;
#pragma unroll
        for (int r = 0; r < 4; ++r) {
          int row = m0 + wr * 128 + i8 * 16 + quad * 4 + r;
          kb[(size_t)row * 1024 + col] = f2bf(acc[i8][j][r]);
        }
      }
  } else {
    const int bb_ = m0 >> 12;
#pragma unroll
    for (int i8 = 0; i8 < 8; ++i8) {
      int kvr = (m0 & 4095) + wr * 128 + i8 * 16 + quad * 4;
#pragma unroll
      for (int j = 0; j < 4; ++j) {
        int c = (n0 - 1024) + wc * 64 + j * 16 + l15;
        int h = c >> 6, dh = c & 63;
        uint2 st;
        st.x = pack2(acc[i8][j][0], acc[i8][j][1]);
        st.y = pack2(acc[i8][j][2], acc[i8][j][3]);
        *(uint2*)&vTb[((size_t)((bb_ * 16 + h) * 64 + dh)) * NKV_ + kvr] = st;
      }
    }
  }
#undef STAGE_A
#undef STAGE_B
#undef LDA2
#undef LDB2
#undef MF
}

// ---------------- out-proj GEMM: 64x128 tiles, tri-buffered counted-vmcnt pipeline ------
// R8-ledger applied to the 2-barrier loop: stage tile i+2 while computing tile i;
// vmcnt(3) after MFMA completes stage(i+1) with stage(i+2) in flight (2 iters of cover).
// body(i-1)'s vmcnt(3)+barrier guarantees buf(i) complete before any wave's ds_read;
// STAGE(i+2)'s WAR target (buf (i-1)%3) was fenced by body(i-1)'s trailing barrier.
__global__ __launch_bounds__(256) void out_gemm(const u16* __restrict__ A,
                                                const u16* __restrict__ Bt,
                                                float* __restrict__ Cout,
                                                const float* __restrict__ bias) {
  __shared__ __align__(16) u16 As[3][64 * 32];    // 12 KB
  __shared__ __align__(16) u16 Bs[3][128 * 32];   // 24 KB
  const int tid = threadIdx.x;
  const int lane = tid & 63;
  const int w = tid >> 6;
  const int wr = w >> 1, wc = w & 1;           // wave covers 32M x 64N
  const int l15 = lane & 15, quad = lane >> 4;
  const int unit = blockIdx.x;
  const int m0 = (unit >> 3) * 64, n0 = (unit & 7) * 128;
  const int K = 1024, N = 1024;

  const u16* Ab = A + (size_t)m0 * K;
  const u16* Bb = Bt + (size_t)n0 * K;
  f32x4 acc[2][4] = {};

  const int ar = tid >> 2, ac = (tid & 3) << 3;          // A: 256 chunks, 1/thread
  const int q1 = w * 64 + lane, q2 = q1 + 256;           // B: 512 chunks, 2/thread
  const int br1 = q1 >> 2, bc1 = (q1 & 3) << 3;
  const int br2 = q2 >> 2, bc2 = (q2 & 3) << 3;

#define STG(bi, k0) do { \
    gload16(Ab + (size_t)ar * K + (k0) + ac, &As[bi][w * 512]); \
    gload16(Bb + (size_t)br1 * K + (k0) + bc1, &Bs[bi][w * 512]); \
    gload16(Bb + (size_t)br2 * K + (k0) + bc2, &Bs[bi][2048 + w * 512]); \
  } while (0)

  STG(0, 0);
  STG(1, 32);
  asm volatile("s_waitcnt vmcnt(3)" ::: "memory");   // STG(0) complete, STG(1) in flight
  __builtin_amdgcn_s_barrier();

  for (int it = 0; it < 32; ++it) {
    const int cur = it % 3;
    bf16x8 af[2], bfr[4];
#pragma unroll
    for (int i = 0; i < 2; ++i)
      af[i] = *(const bf16x8*)&As[cur][(wr * 32 + i * 16 + l15) * 32 + quad * 8];
#pragma unroll
    for (int j = 0; j < 4; ++j)
      bfr[j] = *(const bf16x8*)&Bs[cur][(wc * 64 + j * 16 + l15) * 32 + quad * 8];
    if (it + 2 < 32) STG((it + 2) % 3, (it + 2) * 32);
    __builtin_amdgcn_s_barrier();
    asm volatile("s_waitcnt lgkmcnt(0)" ::: "memory");
    __builtin_amdgcn_s_setprio(1);
#pragma unroll
    for (int i = 0; i < 2; ++i)
#pragma unroll
      for (int j = 0; j < 4; ++j)
        acc[i][j] = __builtin_amdgcn_mfma_f32_16x16x32_bf16(af[i], bfr[j], acc[i][j], 0, 0, 0);
    __builtin_amdgcn_s_setprio(0);
    if (it + 2 < 32)      { asm volatile("s_waitcnt vmcnt(3)" ::: "memory"); }
    else if (it + 2 == 32){ asm volatile("s_waitcnt vmcnt(0)" ::: "memory"); }
    __builtin_amdgcn_s_barrier();
  }
#undef STG

#pragma unroll
  for (int i = 0; i < 2; ++i)
#pragma unroll
    for (int j = 0; j < 4; ++j) {
      int col = n0 + wc * 64 + j * 16 + l15;
      float bv = bias[col];
#pragma unroll
      for (int r = 0; r < 4; ++r) {
        int row = m0 + wr * 32 + i * 16 + quad * 4 + r;
        Cout[(size_t)row * N + col] = acc[i][j][r] + bv;
      }
    }
}

// ---------------- flash attention + FUSED Q-PROJECTION prologue (R9-proven) -------------
__global__ __launch_bounds__(256, 2) void attn_kernel(const u16* __restrict__ xb,
                                                      const u16* __restrict__ WqT,
                                                      const u16* __restrict__ kb,
                                                      const u16* __restrict__ vT,
                                                      u16* __restrict__ attn_out) {
  __shared__ __align__(16) u16 Ks[128 * 64];       // [kv][dh], 16B groups XOR-swizzled
  __shared__ __align__(16) u16 Vs[64 * 128];       // [dh][kv], XOR-swizzled (16 groups/row)
  __shared__ __align__(16) u32 P32[4 * 4 * 16 * 20]; // [w][t][q=l15][20]: wave-private pairs
  __shared__ float Lr[4][4][16];                   // [w][t][q] partial l

  const int tid = threadIdx.x;
  const int lane = tid & 63;
  const int w = tid >> 6;
  const int l15 = lane & 15, quad = lane >> 4;
  const int bh = blockIdx.x, b = bh >> 4, h = bh & 15;
  const int q0 = blockIdx.y * 64;

  const float SC = 0.125f * 1.44269504088896340736f;   // dh^-0.5 * log2(e)
  union { u16 s[8]; bf16x8 v; } qf[4][2];

  // ---- Q-projection prologue ----
  {
    const u16* Axb = xb + (size_t)(b * NQ_ + q0) * 1024;     // 64 rows of x (bf16)
    const u16* Bwq = WqT + (size_t)(h * 64) * 1024;          // 64 Wq-columns (rows of WqT)
    const int c1 = tid, c2 = tid + 256;
    const int r1 = c1 >> 3, g1 = c1 & 7;
    const int r2 = c2 >> 3, g2 = c2 & 7;
    const size_t sO1 = (size_t)r1 * 1024 + (size_t)((g1 ^ (r1 & 7)) << 3);
    const size_t sO2 = (size_t)r2 * 1024 + (size_t)((g2 ^ (r2 & 7)) << 3);
    f32x4 qacc[4] = {};
    const int x7 = l15 & 7;
    for (int k0 = 0; k0 < 1024; k0 += 64) {
      __syncthreads();
      gload16(Axb + sO1 + k0, &Ks[w * 512]);            // A chunks [0,256)
      gload16(Axb + sO2 + k0, &Ks[2048 + w * 512]);     // A chunks [256,512)
      gload16(Bwq + sO1 + k0, &Ks[4096 + w * 512]);     // B chunks [0,256)
      gload16(Bwq + sO2 + k0, &Ks[6144 + w * 512]);     // B chunks [256,512)
      __syncthreads();
      bf16x8 af[2], bfr[4][2];
#pragma unroll
      for (int kc = 0; kc < 2; ++kc) {
        af[kc] = *(const bf16x8*)&Ks[(w * 16 + l15) * 64 + (((kc * 4 + quad) ^ x7) << 3)];
#pragma unroll
        for (int j = 0; j < 4; ++j)
          bfr[j][kc] = *(const bf16x8*)
            &Ks[4096 + (j * 16 + l15) * 64 + (((kc * 4 + quad) ^ x7) << 3)];
      }
#pragma unroll
      for (int j = 0; j < 4; ++j) {
        qacc[j] = __builtin_amdgcn_mfma_f32_16x16x32_bf16(af[0], bfr[j][0], qacc[j], 0, 0, 0);
        qacc[j] = __builtin_amdgcn_mfma_f32_16x16x32_bf16(af[1], bfr[j][1], qacc[j], 0, 0, 0);
      }
    }
    // bounce: Vs as 64x64 f32, col' = col ^ ((row&7)*8)
    float* Q64 = (float*)Vs;
#pragma unroll
    for (int j = 0; j < 4; ++j)
#pragma unroll
      for (int r = 0; r < 4; ++r) {
        int row = w * 16 + quad * 4 + r;
        Q64[row * 64 + ((j * 16 + l15) ^ ((row & 7) * 8))] = qacc[j][r];
      }
    __syncthreads();
#pragma unroll
    for (int t = 0; t < 4; ++t)
#pragma unroll
      for (int kc = 0; kc < 2; ++kc) {
        const float* qp = Q64 + (t * 16 + l15) * 64 + (((kc * 4 + quad) ^ x7) * 8);
        f32x4 lo = *(const f32x4*)qp;
        f32x4 hi = *(const f32x4*)(qp + 4);
#pragma unroll
        for (int e = 0; e < 4; ++e) {
          qf[t][kc].s[e]     = f2bf(lo[e] * SC);
          qf[t][kc].s[e + 4] = f2bf(hi[e] * SC);
        }
      }
    __syncthreads();   // all waves done reading Vs before STAGEKV overwrites it
  }

#define STAGEKV(j0) do { \
    _Pragma("unroll") \
    for (int i_ = 0; i_ < 4; ++i_) { \
      int s_ = i_ * 256 + tid; \
      int kr = s_ >> 3, kg = (s_ ^ kr) & 7; \
      gload16(kb + (size_t)(b * NKV_ + (j0) + kr) * 1024 + h * 64 + kg * 8, \
              &Ks[(i_ * 256 + w * 64) * 8]); \
      int vr = s_ >> 4, vg = (s_ ^ vr) & 15; \
      gload16(vT + (size_t)(bh * 64 + vr) * NKV_ + (j0) + vg * 8, \
              &Vs[(i_ * 256 + w * 64) * 8]); \
    } \
  } while (0)

  f32x4 Oacc[4][4] = {};
  float l_lane[4] = {0.f, 0.f, 0.f, 0.f};

  STAGEKV(0);                                // prologue: tile 0

  for (int it = 0; it < 32; ++it) {
    __syncthreads();                         // tile `it` staged (vmcnt drained per-wave)

    // fragment reads for tile `it` (this wave's complete K/V consumption)
    bf16x8 kf[2][2];
#pragma unroll
    for (int kvt = 0; kvt < 2; ++kvt)
#pragma unroll
      for (int kc = 0; kc < 2; ++kc)
        kf[kvt][kc] = *(const bf16x8*)
          &Ks[(w * 32 + kvt * 16 + l15) * 64 + (((kc * 4 + quad) ^ l15) & 7) * 8];
    bf16x8 vf[4];
#pragma unroll
    for (int d = 0; d < 4; ++d)
      vf[d] = *(const bf16x8*)
        &Vs[(d * 16 + l15) * 128 + (((w * 4 + quad) ^ l15) & 15) * 8];

    __syncthreads();                         // all waves done reading Ks/Vs

    if (it < 31) STAGEKV((it + 1) * 128);    // overwrite: overlaps full compute below

    f32x4 sacc[2][4] = {};
    __builtin_amdgcn_s_setprio(1);
#pragma unroll
    for (int kvt = 0; kvt < 2; ++kvt)
#pragma unroll
      for (int t = 0; t < 4; ++t)
#pragma unroll
        for (int kc = 0; kc < 2; ++kc)
          sacc[kvt][t] = __builtin_amdgcn_mfma_f32_16x16x32_bf16(
              kf[kvt][kc], qf[t][kc].v, sacc[kvt][t], 0, 0, 0);
    __builtin_amdgcn_s_setprio(0);

#pragma unroll
    for (int kvt = 0; kvt < 2; ++kvt)
#pragma unroll
      for (int t = 0; t < 4; ++t) {
        float p0 = __builtin_amdgcn_exp2f(sacc[kvt][t][0]);
        float p1 = __builtin_amdgcn_exp2f(sacc[kvt][t][1]);
        float p2 = __builtin_amdgcn_exp2f(sacc[kvt][t][2]);
        float p3 = __builtin_amdgcn_exp2f(sacc[kvt][t][3]);
        l_lane[t] += (p0 + p1) + (p2 + p3);
        uint2 pk; pk.x = pack2rn(p0, p1); pk.y = pack2rn(p2, p3);
        *(uint2*)&P32[((w * 4 + t) * 16 + l15) * 20 + kvt * 8 + quad * 2] = pk;
      }

    bf16x8 pf[4];
#pragma unroll
    for (int t = 0; t < 4; ++t)
      pf[t] = *(const bf16x8*)&P32[((w * 4 + t) * 16 + l15) * 20 + quad * 4];
    __builtin_amdgcn_s_setprio(1);
#pragma unroll
    for (int d = 0; d < 4; ++d)
#pragma unroll
      for (int t = 0; t < 4; ++t)
        Oacc[d][t] = __builtin_amdgcn_mfma_f32_16x16x32_bf16(vf[d], pf[t], Oacc[d][t],
                                                             0, 0, 0);
    __builtin_amdgcn_s_setprio(0);
  }
#undef STAGEKV

#pragma unroll
  for (int t = 0; t < 4; ++t) {
    l_lane[t] += __shfl_xor(l_lane[t], 16);
    l_lane[t] += __shfl_xor(l_lane[t], 32);
  }
  if (quad == 0) {
#pragma unroll
    for (int t = 0; t < 4; ++t) Lr[w][t][l15] = l_lane[t];
  }
  __syncthreads();
  float inv = 1.0f / (Lr[0][w][l15] + Lr[1][w][l15] + Lr[2][w][l15] + Lr[3][w][l15]);

  float* red = (float*)P32;
  u16* ob = attn_out + (size_t)(b * NQ_ + q0 + w * 16 + l15) * INNER_ + h * 64;
#pragma unroll
  for (int d = 0; d < 4; ++d) {
    __syncthreads();
#pragma unroll
    for (int t = 0; t < 4; ++t)
      *(f32x4*)&red[(w * 4 + t) * 256 + quad * 64 + l15 * 4] = Oacc[d][t];
    __syncthreads();
    f32x4 r = *(const f32x4*)&red[(0 * 4 + w) * 256 + quad * 64 + l15 * 4];
#pragma unroll
    for (int ww = 1; ww < 4; ++ww) {
      f32x4 c = *(const f32x4*)&red[(ww * 4 + w) * 256 + quad * 64 + l15 * 4];
      r[0] += c[0]; r[1] += c[1]; r[2] += c[2]; r[3] += c[3];
    }
    *(u32*)(ob + d * 16 + quad * 4)     = pack2(r[0] * inv, r[1] * inv);
    *(u32*)(ob + d * 16 + quad * 4 + 2) = pack2(r[2] * inv, r[3] * inv);
  }
}

// ---------------- driver ----------------
extern "C" void kernel_launch(void* const* d_in, const int* in_sizes, int n_in,
                              void* d_out, int out_size, void* d_ws, size_t ws_size,
                              hipStream_t stream) {
  const float* x    = (const float*)d_in[0];
  const float* ctx  = (const float*)d_in[1];
  const float* Wq   = (const float*)d_in[2];
  const float* Wkv  = (const float*)d_in[3];
  const float* Wout = (const float*)d_in[4];
  const float* bout = (const float*)d_in[5];

  char* ws = (char*)d_ws;
  u16* xb    = (u16*)(ws + (size_t)( 0u << 20));  // 4 MB  [live through attn prologue]
  u16* ctxb  = (u16*)(ws + (size_t)( 4u << 20));  // 16 MB [dead after kv_gemm]
  u16* WqT   = (u16*)(ws + (size_t)(20u << 20));  // 2 MB  [live through attn prologue]
  u16* WkvT  = (u16*)(ws + (size_t)(22u << 20));  // 4 MB
  u16* WoutT = (u16*)(ws + (size_t)(26u << 20));  // 2 MB
  u16* ab    = (u16*)(ws + (size_t)(28u << 20));  // 4 MB  [old qb slot; NOT aliasing xb]
  u16* kb    = (u16*)(ws + (size_t)(32u << 20));  // 16 MB (K row-major bf16)
  u16* vTb   = (u16*)(ws + (size_t)(48u << 20));  // 16 MB (V transposed [bh*64+dh][NKV])

  // casts + weight transposes in one dispatch (fat cast blocks)
  prep<<<5376, 256, 0, stream>>>(x, ctx, Wq, Wkv, Wout, xb, ctxb, WqT, WkvT, WoutT);
  // kv projection: 256 blocks of 256x256, faithful 8-phase, 1 block/CU
  kv_gemm<<<256, 512, 0, stream>>>(ctxb, WkvT, kb, vTb);
  // fused q-projection + softmax attention: 512 blocks x 256 threads
  attn_kernel<<<dim3(32, 16), 256, 0, stream>>>(xb, WqT, kb, vTb, ab);
  // out = attn Wout + b_out : fp32, 256 blocks, tri-buffered pipeline
  out_gemm<<<256, 256, 0, stream>>>(ab, WoutT, (float*)d_out, bout);
}